// Round 5
// baseline (635.542 us; speedup 1.0000x reference)
//
#include <hip/hip_runtime.h>
#include <math.h>

#define T_TOKENS    16384
#define D_MODEL     2048
#define NUM_EXPERTS 256
#define TOP_K       8
#define MARGIN      6e-5f

// d_out layout (floats): idx | weights | affinities | loss
#define OUT_IDX  0
#define OUT_W    (T_TOKENS * TOP_K)
#define OUT_AFF  (2 * T_TOKENS * TOP_K)
#define OUT_LOSS (2 * T_TOKENS * TOP_K + T_TOKENS * NUM_EXPERTS)

// ws layout (bytes)
#define WS_M64_B   ((size_t)0)                                    // double[256*2048] 4MB
#define WS_MH_B    (WS_M64_B + (size_t)NUM_EXPERTS * D_MODEL * 8) // bf16 1MB
#define WS_ML_B    (WS_MH_B  + (size_t)NUM_EXPERTS * D_MODEL * 2) // bf16 1MB
#define WS_SUMP_B  (WS_ML_B  + (size_t)NUM_EXPERTS * D_MODEL * 2) // double[256]
#define WS_CNT_B   (WS_SUMP_B + NUM_EXPERTS * 8)                  // int[256]
#define WS_NMARG_B (WS_CNT_B  + NUM_EXPERTS * 4)                  // int nmarg, int done (+pad)
#define WS_LIST_B  (WS_NMARG_B + 16)                              // int[16384]
#define WS_NCAND_B (WS_LIST_B + (size_t)T_TOKENS * 4)             // int[16384]
#define WS_CAND_B  (WS_NCAND_B + (size_t)T_TOKENS * 4)            // int[16384*64] 4MB
#define WS_CSP_B   (WS_CAND_B + (size_t)T_TOKENS * 64 * 4)        // float[4096*256] 4MB
// Mpart (double[4][256*2048] = 16MB, live A1->A2) exactly aliases
// paff1 (float[16384*256] = 16MB, live affinity->topk). Disjoint lifetimes.
#define WS_MP_B    (WS_CSP_B + (size_t)4096 * 256 * 4)

typedef __attribute__((ext_vector_type(8))) short short8;
typedef __attribute__((ext_vector_type(4))) float f32x4;

__device__ __forceinline__ unsigned short bf16_rne(float x) {
    unsigned u = __float_as_uint(x);
    u += 0x7FFFu + ((u >> 16) & 1u);
    return (unsigned short)(u >> 16);
}
__device__ __forceinline__ float bf16_f32(unsigned short h) {
    return __uint_as_float(((unsigned)h) << 16);
}
__device__ __forceinline__ unsigned ford(float f) {
    unsigned u = __float_as_uint(f);
    return ((int)u >= 0) ? (u | 0x80000000u) : ~u;
}
__device__ __forceinline__ float finv(unsigned o) {
    return (o & 0x80000000u) ? __uint_as_float(o ^ 0x80000000u)
                             : __uint_as_float(~o);
}

// ---------------------------------------------------------------------------
// Kernel A1: partial M = C @ W over a D-quarter. tile 32e x 64k, grid (32,8,4)
// = 1024 blocks (4 blocks/CU for latency hiding).
// ---------------------------------------------------------------------------
__global__ __launch_bounds__(256, 4) void cw_gemm_part(
    const float* __restrict__ C, const float* __restrict__ W,
    double* __restrict__ Mpart)
{
    __shared__ float Cs[32][34];
    __shared__ float Ws[32][68];

    const int tid = threadIdx.x;
    const int tx = tid & 15;
    const int ty = tid >> 4;
    const int e0 = blockIdx.y * 32;
    const int k0 = blockIdx.x * 64;
    const int z  = blockIdx.z;

    double* Mp = Mpart + (size_t)z * NUM_EXPERTS * D_MODEL;
    double acc[2][4] = {{0,0,0,0},{0,0,0,0}};

    for (int d0 = z * 512; d0 < (z + 1) * 512; d0 += 32) {
        {
            const int e = tid >> 3, d4 = (tid & 7) * 4;
            const float4 v = *(const float4*)(C + (size_t)(e0 + e) * D_MODEL + d0 + d4);
            Cs[d4 + 0][e] = v.x; Cs[d4 + 1][e] = v.y;
            Cs[d4 + 2][e] = v.z; Cs[d4 + 3][e] = v.w;
        }
        #pragma unroll
        for (int r = 0; r < 2; ++r) {
            const int idx = tid + r * 256;
            const int d = idx >> 4, k4 = (idx & 15) * 4;
            *(float4*)&Ws[d][k4] =
                *(const float4*)(W + (size_t)(d0 + d) * D_MODEL + k0 + k4);
        }
        __syncthreads();
        #pragma unroll
        for (int dd = 0; dd < 32; ++dd) {
            const float2 a2 = *(const float2*)&Cs[dd][ty * 2];
            const double a0 = (double)a2.x, a1 = (double)a2.y;
            const float4 b4 = *(const float4*)&Ws[dd][tx * 4];
            const double b[4] = {(double)b4.x, (double)b4.y, (double)b4.z, (double)b4.w};
            #pragma unroll
            for (int j = 0; j < 4; ++j) { acc[0][j] += a0 * b[j]; acc[1][j] += a1 * b[j]; }
        }
        __syncthreads();
    }
    #pragma unroll
    for (int i = 0; i < 2; ++i) {
        const int e = e0 + ty * 2 + i;
        #pragma unroll
        for (int j = 0; j < 4; ++j)
            Mp[(size_t)e * D_MODEL + k0 + tx * 4 + j] = acc[i][j];
    }
}

// ---------------------------------------------------------------------------
// Kernel A2: combine 4 D-quarters -> M64, emit bf16 split Mh/Ml. grid 512x256.
// ---------------------------------------------------------------------------
__global__ __launch_bounds__(256) void cw_combine(
    const double* __restrict__ Mpart, double* __restrict__ M64,
    unsigned short* __restrict__ Mh, unsigned short* __restrict__ Ml)
{
    const int i4 = ((int)blockIdx.x * 256 + (int)threadIdx.x) * 4;
    const double* p0 = Mpart;
    const double* p1 = Mpart + (size_t)NUM_EXPERTS * D_MODEL;
    const double* p2 = Mpart + (size_t)2 * NUM_EXPERTS * D_MODEL;
    const double* p3 = Mpart + (size_t)3 * NUM_EXPERTS * D_MODEL;
    unsigned short hi[4], lo[4];
    #pragma unroll
    for (int u = 0; u < 4; ++u) {
        const double v = (p0[i4 + u] + p1[i4 + u]) + (p2[i4 + u] + p3[i4 + u]);
        M64[i4 + u] = v;
        const float f = (float)v;
        hi[u] = bf16_rne(f);
        lo[u] = bf16_rne(f - bf16_f32(hi[u]));
    }
    uint2 wh, wl;
    wh.x = (unsigned)hi[0] | ((unsigned)hi[1] << 16);
    wh.y = (unsigned)hi[2] | ((unsigned)hi[3] << 16);
    wl.x = (unsigned)lo[0] | ((unsigned)lo[1] << 16);
    wl.y = (unsigned)lo[2] | ((unsigned)lo[3] << 16);
    *(uint2*)(Mh + i4) = wh;
    *(uint2*)(Ml + i4) = wl;
}

// ---------------------------------------------------------------------------
// Kernel B: affinity partials via bf16-split MFMA (hh+hl+lh, f32 acc).
// tile 64t x 128e, BK=64, K-split z x 2 (16 chunks each).
// grid (256,2,2) = 1024 blocks, 32KB LDS (H only) -> 4 blocks/CU target
// (16 waves/CU), __launch_bounds__(256,4) caps VGPR at 128.
// M (both hi and lo halves) lives entirely in wave-private REGISTERS,
// single set, reloaded right after consumption (L2-resident, ~2/3-chunk
// prefetch distance covers L2 latency). H is the only shared staging:
// register load -> bf16-split -> ds_write, double-buffered, counted
// discipline (lgkmcnt(0) + raw s_barrier only; no vmcnt drains).
// ---------------------------------------------------------------------------
struct HRegs { float4 a[2][2]; };                 // [kk][half]
struct MRegs { uint4 h[2][2]; uint4 l[2][2]; };   // [j][kk]

__global__ __launch_bounds__(256, 4) void affinity_mfma(
    const float* __restrict__ H, const unsigned short* __restrict__ Mh,
    const unsigned short* __restrict__ Ml,
    float* __restrict__ paff0, float* __restrict__ paff1)
{
    // fragment-order H tiles: per buf: 2kk x 4 t-tiles x (64 lanes x 8 sh).
    __shared__ unsigned short sHh[2][4096], sHl[2][4096];

    const int tid = threadIdx.x;
    const int lane = tid & 63, wv = tid >> 6;
    const int m = lane & 15, quad = lane >> 4;
    const int t0 = (int)blockIdx.x * 64;
    const int e0 = (int)blockIdx.y * 128;
    const int zb = (int)blockIdx.z * 16;     // chunk base (16 chunks of BK=64)

    const int grp = tid >> 6;        // wave id 0..3
    const int q   = (tid >> 4) & 3;  // k-octet within 32
    const int m16 = tid & 15;

    f32x4 acc[4][2];
    #pragma unroll
    for (int i = 0; i < 4; ++i)
        #pragma unroll
        for (int j = 0; j < 2; ++j) acc[i][j] = (f32x4){0.f, 0.f, 0.f, 0.f};

    HRegs RA, RB;   // H prefetch regs (even / odd chunks)
    MRegs M;        // M regs, single set (consume then reload)

    auto loadH = [&](int kc, HRegs& R) {
        const float* hp = H + (size_t)(t0 + grp * 16 + m16) * D_MODEL + (zb + kc) * 64 + q * 8;
        #pragma unroll
        for (int kk = 0; kk < 2; ++kk) {
            R.a[kk][0] = *(const float4*)(hp + kk * 32);
            R.a[kk][1] = *(const float4*)(hp + kk * 32 + 4);
        }
    };
    auto loadM = [&](int kc, MRegs& R) {
        #pragma unroll
        for (int j = 0; j < 2; ++j) {
            const size_t row = (size_t)(e0 + (wv * 2 + j) * 16 + m) * D_MODEL
                             + (zb + kc) * 64 + quad * 8;
            const unsigned short* mph = Mh + row;
            const unsigned short* mpl = Ml + row;
            #pragma unroll
            for (int kk = 0; kk < 2; ++kk) {
                R.h[j][kk] = *(const uint4*)(mph + kk * 32);
                R.l[j][kk] = *(const uint4*)(mpl + kk * 32);
            }
        }
    };
    auto stageH = [&](int b, const HRegs& R) {
        #pragma unroll
        for (int kk = 0; kk < 2; ++kk) {
            const float4 A = R.a[kk][0], B = R.a[kk][1];
            float x[8] = {A.x, A.y, A.z, A.w, B.x, B.y, B.z, B.w};
            unsigned short hi[8], lo[8];
            #pragma unroll
            for (int u = 0; u < 8; ++u) {
                hi[u] = bf16_rne(x[u]);
                lo[u] = bf16_rne(x[u] - bf16_f32(hi[u]));
            }
            uint4 ph, pl;
            ph.x = (unsigned)hi[0] | ((unsigned)hi[1] << 16);
            ph.y = (unsigned)hi[2] | ((unsigned)hi[3] << 16);
            ph.z = (unsigned)hi[4] | ((unsigned)hi[5] << 16);
            ph.w = (unsigned)hi[6] | ((unsigned)hi[7] << 16);
            pl.x = (unsigned)lo[0] | ((unsigned)lo[1] << 16);
            pl.y = (unsigned)lo[2] | ((unsigned)lo[3] << 16);
            pl.z = (unsigned)lo[4] | ((unsigned)lo[5] << 16);
            pl.w = (unsigned)lo[6] | ((unsigned)lo[7] << 16);
            *(uint4*)&sHh[b][kk * 2048 + grp * 512 + lane * 8] = ph;
            *(uint4*)&sHl[b][kk * 2048 + grp * 512 + lane * 8] = pl;
        }
    };
    auto mfmaT = [&](int b, const MRegs& RM) {
        #pragma unroll
        for (int kk = 0; kk < 2; ++kk) {
            short8 ah[4], al[4], bh[2], bl[2];
            #pragma unroll
            for (int i = 0; i < 4; ++i) {
                ah[i] = *(const short8*)&sHh[b][kk * 2048 + i * 512 + lane * 8];
                al[i] = *(const short8*)&sHl[b][kk * 2048 + i * 512 + lane * 8];
            }
            #pragma unroll
            for (int j = 0; j < 2; ++j) {
                bh[j] = *(const short8*)&RM.h[j][kk];
                bl[j] = *(const short8*)&RM.l[j][kk];
            }
            __builtin_amdgcn_s_setprio(1);
            #pragma unroll
            for (int i = 0; i < 4; ++i)
                #pragma unroll
                for (int j = 0; j < 2; ++j) {
                    acc[i][j] = __builtin_amdgcn_mfma_f32_16x16x32_bf16(ah[i], bh[j], acc[i][j], 0, 0, 0);
                    acc[i][j] = __builtin_amdgcn_mfma_f32_16x16x32_bf16(ah[i], bl[j], acc[i][j], 0, 0, 0);
                    acc[i][j] = __builtin_amdgcn_mfma_f32_16x16x32_bf16(al[i], bh[j], acc[i][j], 0, 0, 0);
                }
            __builtin_amdgcn_s_setprio(0);
        }
    };

    // prologue: queue LH(0),LH(1),M(0); stageH(0)'s wait on LH(0) retires
    // nothing newer; mfmaT(0)'s wait on M(0) regs retires the rest.
    loadH(0, RA);
    loadH(1, RB);
    loadM(0, M);
    stageH(0, RA);
    asm volatile("s_waitcnt lgkmcnt(0)" ::: "memory");
    __builtin_amdgcn_s_barrier();                   // chunk0 H ready

    for (int k = 0; k < 16; k += 2) {
        // ---- even body: compute chunk k from buf0 ----
        stageH(1, RB);                              // SH(k+1), waits LH(k+1)
        if (k + 2 < 16) loadH(k + 2, RA);           // LH(k+2)
        mfmaT(0, M);                                // CP(k), waits M(k)
        loadM(k + 1, M);                            // M(k+1) (k+1 <= 15)
        asm volatile("s_waitcnt lgkmcnt(0)" ::: "memory");
        __builtin_amdgcn_s_barrier();               // chunk k+1 H ready

        // ---- odd body: compute chunk k+1 from buf1 ----
        if (k + 2 < 16) stageH(0, RA);              // SH(k+2), waits LH(k+2)
        if (k + 3 < 16) loadH(k + 3, RB);           // LH(k+3)
        mfmaT(1, M);                                // CP(k+1), waits M(k+1)
        if (k + 2 < 16) loadM(k + 2, M);            // M(k+2)
        asm volatile("s_waitcnt lgkmcnt(0)" ::: "memory");
        __builtin_amdgcn_s_barrier();               // chunk k+2 H ready
    }

    // epilogue: store f32 partial tile (topk combines the two K-halves)
    float* pz = (blockIdx.z == 0) ? paff0 : paff1;
    #pragma unroll
    for (int j = 0; j < 2; ++j) {
        const int e = e0 + wv * 32 + j * 16 + m;
        #pragma unroll
        for (int i = 0; i < 4; ++i) {
            const int tbase = t0 + i * 16 + quad * 4;
            #pragma unroll
            for (int r = 0; r < 4; ++r)
                pz[(size_t)(tbase + r) * NUM_EXPERTS + e] = acc[i][j][r];
        }
    }
}

// ---------------------------------------------------------------------------
// Kernel C: combine K-split partials -> aff, sigmoid colsum partials,
// fast top-9 (f32) on packed u64 keys + margin test. grid 4096 x 256.
// ---------------------------------------------------------------------------
__global__ __launch_bounds__(256) void topk_margin(
    const float* __restrict__ paff0, const float* __restrict__ paff1,
    const float* __restrict__ bias,
    float* __restrict__ aff, float* __restrict__ csp,
    float* __restrict__ out_idx, float* __restrict__ out_w,
    int* __restrict__ nmarg, int* __restrict__ list,
    int* __restrict__ ncand, int* __restrict__ cand)
{
    __shared__ float sg4[4][NUM_EXPERTS];

    const int tid = threadIdx.x;
    const int lane = tid & 63;
    const int wv = tid >> 6;
    const int t = blockIdx.x * 4 + wv;

    const float4 a0 = *(const float4*)(paff0 + (size_t)t * NUM_EXPERTS + lane * 4);
    const float4 a1 = *(const float4*)(paff1 + (size_t)t * NUM_EXPERTS + lane * 4);
    float4 av;
    av.x = a0.x + a1.x; av.y = a0.y + a1.y;
    av.z = a0.z + a1.z; av.w = a0.w + a1.w;
    *(float4*)(aff + (size_t)t * NUM_EXPERTS + lane * 4) = av;

    const float4 bv = *(const float4*)(bias + lane * 4);
    float g[4], s0[4];
    g[0] = 1.f / (1.f + expf(-av.x)); s0[0] = g[0] + bv.x;
    g[1] = 1.f / (1.f + expf(-av.y)); s0[1] = g[1] + bv.y;
    g[2] = 1.f / (1.f + expf(-av.z)); s0[2] = g[2] + bv.z;
    g[3] = 1.f / (1.f + expf(-av.w)); s0[3] = g[3] + bv.w;

    // per-block sigmoid column partial (all tokens, unconditional)
    *(float4*)&sg4[wv][lane * 4] = *(float4*)g;
    __syncthreads();
    {
        const float s = sg4[0][tid] + sg4[1][tid] + sg4[2][tid] + sg4[3][tid];
        csp[(size_t)blockIdx.x * NUM_EXPERTS + tid] = s;
    }

    unsigned long long kw[4];
    #pragma unroll
    for (int j = 0; j < 4; ++j)
        kw[j] = ((unsigned long long)ford(s0[j]) << 32)
              | (unsigned long long)(0xFFFFFFFFu - (unsigned)(lane * 4 + j));

    float wsum = 0.f, my_g = 0.f, prevs = 0.f, minGap = 1e30f, s8 = 0.f;
    int my_i = 0;

    #pragma unroll
    for (int it = 0; it < 9; ++it) {
        unsigned long long bk = kw[0];
        if (kw[1] > bk) bk = kw[1];
        if (kw[2] > bk) bk = kw[2];
        if (kw[3] > bk) bk = kw[3];
        #pragma unroll
        for (int off = 1; off < 64; off <<= 1) {
            const unsigned long long ok = __shfl_xor(bk, off, 64);
            if (ok > bk) bk = ok;
        }
        const unsigned o = (unsigned)(bk >> 32);
        const float sv = finv(o);
        const int e = (int)(0xFFFFFFFFu - (unsigned)(bk & 0xFFFFFFFFu));
        const int ej = e & 3, el = e >> 2;
        const float gl = (ej == 0) ? g[0] : (ej == 1) ? g[1] : (ej == 2) ? g[2] : g[3];
        const float gv = __shfl(gl, el, 64);
        if (it < TOP_K) {
            wsum += gv;
            if (lane == it) { my_i = e; my_g = gv; }
            if (it == 7) s8 = sv;
        }
        if (it > 0) minGap = fminf(minGap, prevs - sv);
        prevs = sv;
        if (lane == el) {
            if (ej == 0) kw[0] = 0ull; else if (ej == 1) kw[1] = 0ull;
            else if (ej == 2) kw[2] = 0ull; else kw[3] = 0ull;
        }
    }

    if (minGap < MARGIN) {
        int pos = 0;
        if (lane == 0) pos = atomicAdd(nmarg, 1);
        pos = __shfl(pos, 0, 64);
        const float thresh = s8 - MARGIN;
        int base = 0;
        #pragma unroll
        for (int j = 0; j < 4; ++j) {
            const bool c = (s0[j] >= thresh);
            const unsigned long long mk = __ballot(c);
            const int mypos = base + __popcll(mk & ((1ull << lane) - 1ull));
            if (c && mypos < 64) cand[(size_t)pos * 64 + mypos] = lane * 4 + j;
            base += (int)__popcll(mk);
        }
        if (lane == 0) { list[pos] = t; ncand[pos] = min(base, 64); }
    } else {
        const float inv = 1.f / (wsum + 1e-10f);
        if (lane < TOP_K) {
            out_idx[(size_t)t * TOP_K + lane] = (float)my_i;
            out_w[(size_t)t * TOP_K + lane] = my_g * inv;
        }
    }
}

// ---------------------------------------------------------------------------
// Kernel R: candidate-set f64 recheck.
// ---------------------------------------------------------------------------
__global__ __launch_bounds__(256) void recheck2(
    const float* __restrict__ H, const double* __restrict__ M64,
    const float* __restrict__ bias, const int* __restrict__ list,
    const int* __restrict__ ncand, const int* __restrict__ cand,
    const int* __restrict__ nmarg, float* __restrict__ out_idx,
    float* __restrict__ out_w)
{
    __shared__ float hsf[D_MODEL];
    __shared__ double sg[64], ssc[64];

    const int n = *nmarg;
    const int lane = threadIdx.x & 63, wv = threadIdx.x >> 6;

    for (int i = (int)blockIdx.x; i < n; i += (int)gridDim.x) {
        const int t = list[i];
        const int nc = ncand[i];

        for (int qd = threadIdx.x; qd < D_MODEL / 4; qd += 256)
            *(float4*)&hsf[qd * 4] = *(const float4*)(H + (size_t)t * D_MODEL + qd * 4);
        __syncthreads();

        for (int c = wv; c < nc; c += 4) {
            const int e = cand[(size_t)i * 64 + c];
            const double* mrow = M64 + (size_t)e * D_MODEL;
            double acc = 0.0;
            #pragma unroll 8
            for (int j = 0; j < 32; ++j) {
                const int k = lane + 64 * j;
                acc = fma((double)hsf[k], mrow[k], acc);
            }
            #pragma unroll
            for (int off = 1; off < 64; off <<= 1) acc += __shfl_xor(acc, off, 64);
            if (lane == 0) {
                const double gg = 1.0 / (1.0 + exp(-acc));
                sg[c] = gg;
                ssc[c] = gg + (double)bias[e];
            }
        }
        __syncthreads();

        if (wv == 0) {
            double s = -1e300, g = 0.0;
            int id = 1 << 20;
            if (lane < nc) { s = ssc[lane]; g = sg[lane]; id = cand[(size_t)i * 64 + lane]; }

            double wsum = 0.0, my_g = 0.0;
            int my_i = 0;
            for (int it = 0; it < TOP_K; ++it) {
                double bs = s, bg = g; int bi = id;
                #pragma unroll
                for (int off = 1; off < 64; off <<= 1) {
                    const double os = __shfl_xor(bs, off, 64);
                    const double og = __shfl_xor(bg, off, 64);
                    const int    oi = __shfl_xor(bi, off, 64);
                    if (os > bs || (os == bs && oi < bi)) { bs = os; bg = og; bi = oi; }
                }
                wsum += bg;
                if (lane == it) { my_i = bi; my_g = bg; }
                if (id == bi) s = -1e300;
            }
            const double inv = 1.0 / (wsum + 1e-10);
            if (lane < TOP_K) {
                out_idx[(size_t)t * TOP_K + lane] = (float)my_i;
                out_w[(size_t)t * TOP_K + lane] = (float)(my_g * inv);
            }
        }
        __syncthreads();
    }
}

// ---------------------------------------------------------------------------
// Kernel H: histogram out_idx -> counts; reduce csp[4096][256] -> sumP; the
// LAST block (ticket pattern) computes the balance loss. grid 64 x 256.
// ---------------------------------------------------------------------------
__global__ __launch_bounds__(256) void hist_reduce_loss(
    const float* __restrict__ out_idx, const float* __restrict__ csp,
    int* __restrict__ counts, double* __restrict__ sumP,
    int* __restrict__ done, float* __restrict__ out_loss)
{
    __shared__ int h[NUM_EXPERTS];
    __shared__ int ticket;
    const int tid = threadIdx.x;
    const int lane = tid & 63, wv = tid >> 6;
    h[tid] = 0;
    __syncthreads();
    for (int i = (int)blockIdx.x * 256 + tid; i < T_TOKENS * TOP_K; i += 64 * 256)
        atomicAdd(&h[(int)out_idx[i]], 1);
    __syncthreads();
    if (h[tid] != 0) atomicAdd(&counts[tid], h[tid]);

    const int e = (int)blockIdx.x * 4 + wv;
    float ps = 0.f;
    for (int p = lane; p < 4096; p += 64)
        ps += csp[(size_t)p * NUM_EXPERTS + e];
    #pragma unroll
    for (int off = 1; off < 64; off <<= 1) ps += __shfl_xor(ps, off, 64);
    if (lane == 0) sumP[e] = (double)ps;

    // last-block loss
    __threadfence();
    __syncthreads();
    if (tid == 0) ticket = atomicAdd(done, 1);
    __syncthreads();
    if (ticket == 63) {
        __shared__ double red[256];
        const int c = atomicAdd(&counts[tid], 0);          // coherent read
        const double sp = atomicAdd(&sumP[tid], 0.0);      // coherent read
        red[tid] = (double)c * sp;
        __syncthreads();
        #pragma unroll
        for (int sft = 128; sft > 0; sft >>= 1) {
            if (tid < sft) red[tid] += red[tid + sft];
            __syncthreads();
        }
        if (tid == 0) {
            const double denom = (double)T_TOKENS * (double)TOP_K * (double)T_TOKENS;
            out_loss[0] = (float)(0.001 * ((double)NUM_EXPERTS / (double)TOP_K) * red[0] / denom);
        }
    }
}

extern "C" void kernel_launch(void* const* d_in, const int* in_sizes, int n_in,
                              void* d_out, int out_size, void* d_ws, size_t ws_size,
                              hipStream_t stream) {
    (void)in_sizes; (void)n_in; (void)out_size; (void)ws_size;
    const float* hidden = (const float*)d_in[0];
    const float* W      = (const float*)d_in[1];
    const float* C      = (const float*)d_in[2];
    const float* bias   = (const float*)d_in[3];
    float* out = (float*)d_out;
    char* ws   = (char*)d_ws;

    double*         M64    = (double*)(ws + WS_M64_B);
    unsigned short* Mh     = (unsigned short*)(ws + WS_MH_B);
    unsigned short* Ml     = (unsigned short*)(ws + WS_ML_B);
    double*         sumP   = (double*)(ws + WS_SUMP_B);
    int*            counts = (int*)(ws + WS_CNT_B);
    int*            nmarg  = (int*)(ws + WS_NMARG_B);
    int*            done   = (int*)(ws + WS_NMARG_B) + 1;
    int*            list   = (int*)(ws + WS_LIST_B);
    int*            ncand  = (int*)(ws + WS_NCAND_B);
    int*            cand   = (int*)(ws + WS_CAND_B);
    float*          csp    = (float*)(ws + WS_CSP_B);
    double*         Mpart  = (double*)(ws + WS_MP_B);   // 16MB, dead after A2
    float*          paff1  = (float*)(ws + WS_MP_B);    // 16MB, alias (disjoint lifetime)

    hipMemsetAsync(ws + WS_CNT_B, 0, NUM_EXPERTS * 4 + 16, stream);

    cw_gemm_part<<<dim3(D_MODEL / 64, NUM_EXPERTS / 32, 4), 256, 0, stream>>>(C, W, Mpart);
    cw_combine<<<dim3(NUM_EXPERTS * D_MODEL / 1024), 256, 0, stream>>>(Mpart, M64, Mh, Ml);

    affinity_mfma<<<dim3(T_TOKENS / 64, 2, 2), 256, 0, stream>>>(
        hidden, Mh, Ml, out + OUT_AFF, paff1);

    topk_margin<<<dim3(T_TOKENS / 4), 256, 0, stream>>>(
        out + OUT_AFF, paff1, bias, out + OUT_AFF, csp,
        out + OUT_IDX, out + OUT_W, nmarg, list, ncand, cand);

    recheck2<<<dim3(2048), 256, 0, stream>>>(
        hidden, M64, bias, list, ncand, cand, nmarg, out + OUT_IDX, out + OUT_W);

    hist_reduce_loss<<<dim3(64), 256, 0, stream>>>(
        out + OUT_IDX, csp, counts, sumP, done, out + OUT_LOSS);
}

// Round 6
// 469.535 us; speedup vs baseline: 1.3536x; 1.3536x over previous
//
#include <hip/hip_runtime.h>
#include <math.h>

#define T_TOKENS    16384
#define D_MODEL     2048
#define NUM_EXPERTS 256
#define TOP_K       8
#define MARGIN      6e-5f

// d_out layout (floats): idx | weights | affinities | loss
#define OUT_IDX  0
#define OUT_W    (T_TOKENS * TOP_K)
#define OUT_AFF  (2 * T_TOKENS * TOP_K)
#define OUT_LOSS (2 * T_TOKENS * TOP_K + T_TOKENS * NUM_EXPERTS)

// ws layout (bytes)
#define WS_M64_B   ((size_t)0)                                    // double[256*2048] 4MB
#define WS_MH_B    (WS_M64_B + (size_t)NUM_EXPERTS * D_MODEL * 8) // bf16 1MB (fragment order)
#define WS_ML_B    (WS_MH_B  + (size_t)NUM_EXPERTS * D_MODEL * 2) // bf16 1MB (fragment order)
#define WS_SUMP_B  (WS_ML_B  + (size_t)NUM_EXPERTS * D_MODEL * 2) // double[256]
#define WS_CNT_B   (WS_SUMP_B + NUM_EXPERTS * 8)                  // int[256]
#define WS_NMARG_B (WS_CNT_B  + NUM_EXPERTS * 4)                  // int nmarg, int done (+pad)
#define WS_LIST_B  (WS_NMARG_B + 16)                              // int[16384]
#define WS_NCAND_B (WS_LIST_B + (size_t)T_TOKENS * 4)             // int[16384]
#define WS_CAND_B  (WS_NCAND_B + (size_t)T_TOKENS * 4)            // int[16384*64] 4MB
#define WS_CSP_B   (WS_CAND_B + (size_t)T_TOKENS * 64 * 4)        // float[4096*256] 4MB
// Mpart (double[4][256*2048] = 16MB, live A1->A2) exactly aliases
// paff1 (float[16384*256] = 16MB, live affinity->topk). Disjoint lifetimes.
#define WS_MP_B    (WS_CSP_B + (size_t)4096 * 256 * 4)

typedef __attribute__((ext_vector_type(8))) short short8;
typedef __attribute__((ext_vector_type(4))) float f32x4;

__device__ __forceinline__ unsigned short bf16_rne(float x) {
    unsigned u = __float_as_uint(x);
    u += 0x7FFFu + ((u >> 16) & 1u);
    return (unsigned short)(u >> 16);
}
__device__ __forceinline__ float bf16_f32(unsigned short h) {
    return __uint_as_float(((unsigned)h) << 16);
}
__device__ __forceinline__ unsigned ford(float f) {
    unsigned u = __float_as_uint(f);
    return ((int)u >= 0) ? (u | 0x80000000u) : ~u;
}
__device__ __forceinline__ float finv(unsigned o) {
    return (o & 0x80000000u) ? __uint_as_float(o ^ 0x80000000u)
                             : __uint_as_float(~o);
}

// ---------------------------------------------------------------------------
// Kernel A1: partial M = C @ W over a D-quarter. tile 32e x 64k, grid (32,8,4)
// = 1024 blocks (4 blocks/CU for latency hiding).
// ---------------------------------------------------------------------------
__global__ __launch_bounds__(256, 4) void cw_gemm_part(
    const float* __restrict__ C, const float* __restrict__ W,
    double* __restrict__ Mpart)
{
    __shared__ float Cs[32][34];
    __shared__ float Ws[32][68];

    const int tid = threadIdx.x;
    const int tx = tid & 15;
    const int ty = tid >> 4;
    const int e0 = blockIdx.y * 32;
    const int k0 = blockIdx.x * 64;
    const int z  = blockIdx.z;

    double* Mp = Mpart + (size_t)z * NUM_EXPERTS * D_MODEL;
    double acc[2][4] = {{0,0,0,0},{0,0,0,0}};

    for (int d0 = z * 512; d0 < (z + 1) * 512; d0 += 32) {
        {
            const int e = tid >> 3, d4 = (tid & 7) * 4;
            const float4 v = *(const float4*)(C + (size_t)(e0 + e) * D_MODEL + d0 + d4);
            Cs[d4 + 0][e] = v.x; Cs[d4 + 1][e] = v.y;
            Cs[d4 + 2][e] = v.z; Cs[d4 + 3][e] = v.w;
        }
        #pragma unroll
        for (int r = 0; r < 2; ++r) {
            const int idx = tid + r * 256;
            const int d = idx >> 4, k4 = (idx & 15) * 4;
            *(float4*)&Ws[d][k4] =
                *(const float4*)(W + (size_t)(d0 + d) * D_MODEL + k0 + k4);
        }
        __syncthreads();
        #pragma unroll
        for (int dd = 0; dd < 32; ++dd) {
            const float2 a2 = *(const float2*)&Cs[dd][ty * 2];
            const double a0 = (double)a2.x, a1 = (double)a2.y;
            const float4 b4 = *(const float4*)&Ws[dd][tx * 4];
            const double b[4] = {(double)b4.x, (double)b4.y, (double)b4.z, (double)b4.w};
            #pragma unroll
            for (int j = 0; j < 4; ++j) { acc[0][j] += a0 * b[j]; acc[1][j] += a1 * b[j]; }
        }
        __syncthreads();
    }
    #pragma unroll
    for (int i = 0; i < 2; ++i) {
        const int e = e0 + ty * 2 + i;
        #pragma unroll
        for (int j = 0; j < 4; ++j)
            Mp[(size_t)e * D_MODEL + k0 + tx * 4 + j] = acc[i][j];
    }
}

// ---------------------------------------------------------------------------
// Kernel A2: combine 4 D-quarters -> M64 (row-major), emit bf16 split Mh/Ml
// in MFMA FRAGMENT order: short index
//   ((e16*64 + kc)*64 + q*16 + m16)*8 + jj
// with e16=e>>4, m16=e&15, kc=k>>5, q=(k>>3)&3, jj=k&7.  A wave's B-fragment
// for (e-tile e16, chunk kc) is then 64 lanes x 8 shorts CONTIGUOUS (1KB).
// ---------------------------------------------------------------------------
__global__ __launch_bounds__(256) void cw_combine(
    const double* __restrict__ Mpart, double* __restrict__ M64,
    unsigned short* __restrict__ Mh, unsigned short* __restrict__ Ml)
{
    const int i4 = ((int)blockIdx.x * 256 + (int)threadIdx.x) * 4;
    const double* p0 = Mpart;
    const double* p1 = Mpart + (size_t)NUM_EXPERTS * D_MODEL;
    const double* p2 = Mpart + (size_t)2 * NUM_EXPERTS * D_MODEL;
    const double* p3 = Mpart + (size_t)3 * NUM_EXPERTS * D_MODEL;
    unsigned short hi[4], lo[4];
    #pragma unroll
    for (int u = 0; u < 4; ++u) {
        const double v = (p0[i4 + u] + p1[i4 + u]) + (p2[i4 + u] + p3[i4 + u]);
        M64[i4 + u] = v;
        const float f = (float)v;
        hi[u] = bf16_rne(f);
        lo[u] = bf16_rne(f - bf16_f32(hi[u]));
    }
    uint2 wh, wl;
    wh.x = (unsigned)hi[0] | ((unsigned)hi[1] << 16);
    wh.y = (unsigned)hi[2] | ((unsigned)hi[3] << 16);
    wl.x = (unsigned)lo[0] | ((unsigned)lo[1] << 16);
    wl.y = (unsigned)lo[2] | ((unsigned)lo[3] << 16);
    const int e = i4 >> 11;          // row (expert)
    const int k = i4 & 2047;         // col, multiple of 4
    const int base = (((e >> 4) * 64 + (k >> 5)) * 64 + ((k >> 3) & 3) * 16 + (e & 15)) * 8
                   + (k & 7);        // jj in {0,4}: uint2 stays 8B-aligned
    *(uint2*)(Mh + base) = wh;
    *(uint2*)(Ml + base) = wl;
}

// ---------------------------------------------------------------------------
// Kernel B: affinity partials via bf16-split MFMA (hh+hl+lh, f32 acc).
// ZERO LDS, ZERO barriers. Block = 64t x 128e, 4 waves (each 64t x 32e),
// BK=32, K-split z x 2 (32 chunks each). grid (256,2,2) = 1024 blocks.
// H loaded f32 per-lane in fragment position (row m, octet quad) and split
// in-register (2x conversion redundancy across e-blocks, same as R4);
// M loaded as coalesced per-lane uint4 from the fragment-order Mh/Ml.
// __launch_bounds__(256,3): 170-VGPR cap vs ~130 demand (R5 lesson: headroom)
// -> 3 blocks/CU = 12 waves/CU, all waves fully independent.
// ---------------------------------------------------------------------------
__global__ __launch_bounds__(256, 3) void affinity_mfma(
    const float* __restrict__ H, const unsigned short* __restrict__ Mh,
    const unsigned short* __restrict__ Ml,
    float* __restrict__ paff0, float* __restrict__ paff1)
{
    const int tid = threadIdx.x;
    const int lane = tid & 63, wv = tid >> 6;
    const int m = lane & 15, quad = lane >> 4;
    const int t0 = (int)blockIdx.x * 64;
    const int e0 = (int)blockIdx.y * 128;
    const int e16b = (int)blockIdx.y * 8;     // e-tile base (16-expert tiles)
    const int zb = (int)blockIdx.z * 32;      // chunk base (BK=32 chunks)

    f32x4 acc[4][2];
    #pragma unroll
    for (int i = 0; i < 4; ++i)
        #pragma unroll
        for (int j = 0; j < 2; ++j) acc[i][j] = (f32x4){0.f, 0.f, 0.f, 0.f};

    // hoisted base pointers (advance by compile-time-constant strides)
    const float* hb[4];
    #pragma unroll
    for (int i = 0; i < 4; ++i)
        hb[i] = H + (size_t)(t0 + i * 16 + m) * D_MODEL + zb * 32 + quad * 8;
    const unsigned short* mhb[2];
    const unsigned short* mlb[2];
    #pragma unroll
    for (int j = 0; j < 2; ++j) {
        const size_t mb = ((size_t)((e16b + wv * 2 + j) * 64 + zb) * 64 + lane) * 8;
        mhb[j] = Mh + mb;
        mlb[j] = Ml + mb;
    }

    for (int kc = 0; kc < 32; ++kc) {
        // ---- loads (plain; compiler pipelines across iterations) ----
        float4 hf[4][2];
        #pragma unroll
        for (int i = 0; i < 4; ++i) {
            const float* hp = hb[i] + kc * 32;
            hf[i][0] = *(const float4*)hp;
            hf[i][1] = *(const float4*)(hp + 4);
        }
        uint4 bhw[2], blw[2];
        #pragma unroll
        for (int j = 0; j < 2; ++j) {
            bhw[j] = *(const uint4*)(mhb[j] + kc * 512);
            blw[j] = *(const uint4*)(mlb[j] + kc * 512);
        }
        // ---- in-register bf16 split of H (identical math to R4 stageH) ----
        uint4 ph[4], pl[4];
        #pragma unroll
        for (int i = 0; i < 4; ++i) {
            const float x[8] = {hf[i][0].x, hf[i][0].y, hf[i][0].z, hf[i][0].w,
                                hf[i][1].x, hf[i][1].y, hf[i][1].z, hf[i][1].w};
            unsigned short h8[8], l8[8];
            #pragma unroll
            for (int u = 0; u < 8; ++u) {
                h8[u] = bf16_rne(x[u]);
                l8[u] = bf16_rne(x[u] - bf16_f32(h8[u]));
            }
            ph[i].x = (unsigned)h8[0] | ((unsigned)h8[1] << 16);
            ph[i].y = (unsigned)h8[2] | ((unsigned)h8[3] << 16);
            ph[i].z = (unsigned)h8[4] | ((unsigned)h8[5] << 16);
            ph[i].w = (unsigned)h8[6] | ((unsigned)h8[7] << 16);
            pl[i].x = (unsigned)l8[0] | ((unsigned)l8[1] << 16);
            pl[i].y = (unsigned)l8[2] | ((unsigned)l8[3] << 16);
            pl[i].z = (unsigned)l8[4] | ((unsigned)l8[5] << 16);
            pl[i].w = (unsigned)l8[6] | ((unsigned)l8[7] << 16);
        }
        // ---- 24 MFMA (same order as R4/R5: i, j, hh/hl/lh) ----
        __builtin_amdgcn_s_setprio(1);
        #pragma unroll
        for (int i = 0; i < 4; ++i) {
            const short8 ah = *(const short8*)&ph[i];
            const short8 al = *(const short8*)&pl[i];
            #pragma unroll
            for (int j = 0; j < 2; ++j) {
                const short8 bh = *(const short8*)&bhw[j];
                const short8 bl = *(const short8*)&blw[j];
                acc[i][j] = __builtin_amdgcn_mfma_f32_16x16x32_bf16(ah, bh, acc[i][j], 0, 0, 0);
                acc[i][j] = __builtin_amdgcn_mfma_f32_16x16x32_bf16(ah, bl, acc[i][j], 0, 0, 0);
                acc[i][j] = __builtin_amdgcn_mfma_f32_16x16x32_bf16(al, bh, acc[i][j], 0, 0, 0);
            }
        }
        __builtin_amdgcn_s_setprio(0);
    }

    // epilogue: store f32 partial tile (topk combines the two K-halves)
    float* pz = (blockIdx.z == 0) ? paff0 : paff1;
    #pragma unroll
    for (int j = 0; j < 2; ++j) {
        const int e = e0 + wv * 32 + j * 16 + m;
        #pragma unroll
        for (int i = 0; i < 4; ++i) {
            const int tbase = t0 + i * 16 + quad * 4;
            #pragma unroll
            for (int r = 0; r < 4; ++r)
                pz[(size_t)(tbase + r) * NUM_EXPERTS + e] = acc[i][j][r];
        }
    }
}

// ---------------------------------------------------------------------------
// Kernel C: combine K-split partials -> aff, sigmoid colsum partials,
// fast top-9 (f32) on packed u64 keys + margin test. grid 4096 x 256.
// ---------------------------------------------------------------------------
__global__ __launch_bounds__(256) void topk_margin(
    const float* __restrict__ paff0, const float* __restrict__ paff1,
    const float* __restrict__ bias,
    float* __restrict__ aff, float* __restrict__ csp,
    float* __restrict__ out_idx, float* __restrict__ out_w,
    int* __restrict__ nmarg, int* __restrict__ list,
    int* __restrict__ ncand, int* __restrict__ cand)
{
    __shared__ float sg4[4][NUM_EXPERTS];

    const int tid = threadIdx.x;
    const int lane = tid & 63;
    const int wv = tid >> 6;
    const int t = blockIdx.x * 4 + wv;

    const float4 a0 = *(const float4*)(paff0 + (size_t)t * NUM_EXPERTS + lane * 4);
    const float4 a1 = *(const float4*)(paff1 + (size_t)t * NUM_EXPERTS + lane * 4);
    float4 av;
    av.x = a0.x + a1.x; av.y = a0.y + a1.y;
    av.z = a0.z + a1.z; av.w = a0.w + a1.w;
    *(float4*)(aff + (size_t)t * NUM_EXPERTS + lane * 4) = av;

    const float4 bv = *(const float4*)(bias + lane * 4);
    float g[4], s0[4];
    g[0] = 1.f / (1.f + expf(-av.x)); s0[0] = g[0] + bv.x;
    g[1] = 1.f / (1.f + expf(-av.y)); s0[1] = g[1] + bv.y;
    g[2] = 1.f / (1.f + expf(-av.z)); s0[2] = g[2] + bv.z;
    g[3] = 1.f / (1.f + expf(-av.w)); s0[3] = g[3] + bv.w;

    // per-block sigmoid column partial (all tokens, unconditional)
    *(float4*)&sg4[wv][lane * 4] = *(float4*)g;
    __syncthreads();
    {
        const float s = sg4[0][tid] + sg4[1][tid] + sg4[2][tid] + sg4[3][tid];
        csp[(size_t)blockIdx.x * NUM_EXPERTS + tid] = s;
    }

    unsigned long long kw[4];
    #pragma unroll
    for (int j = 0; j < 4; ++j)
        kw[j] = ((unsigned long long)ford(s0[j]) << 32)
              | (unsigned long long)(0xFFFFFFFFu - (unsigned)(lane * 4 + j));

    float wsum = 0.f, my_g = 0.f, prevs = 0.f, minGap = 1e30f, s8 = 0.f;
    int my_i = 0;

    #pragma unroll
    for (int it = 0; it < 9; ++it) {
        unsigned long long bk = kw[0];
        if (kw[1] > bk) bk = kw[1];
        if (kw[2] > bk) bk = kw[2];
        if (kw[3] > bk) bk = kw[3];
        #pragma unroll
        for (int off = 1; off < 64; off <<= 1) {
            const unsigned long long ok = __shfl_xor(bk, off, 64);
            if (ok > bk) bk = ok;
        }
        const unsigned o = (unsigned)(bk >> 32);
        const float sv = finv(o);
        const int e = (int)(0xFFFFFFFFu - (unsigned)(bk & 0xFFFFFFFFu));
        const int ej = e & 3, el = e >> 2;
        const float gl = (ej == 0) ? g[0] : (ej == 1) ? g[1] : (ej == 2) ? g[2] : g[3];
        const float gv = __shfl(gl, el, 64);
        if (it < TOP_K) {
            wsum += gv;
            if (lane == it) { my_i = e; my_g = gv; }
            if (it == 7) s8 = sv;
        }
        if (it > 0) minGap = fminf(minGap, prevs - sv);
        prevs = sv;
        if (lane == el) {
            if (ej == 0) kw[0] = 0ull; else if (ej == 1) kw[1] = 0ull;
            else if (ej == 2) kw[2] = 0ull; else kw[3] = 0ull;
        }
    }

    if (minGap < MARGIN) {
        int pos = 0;
        if (lane == 0) pos = atomicAdd(nmarg, 1);
        pos = __shfl(pos, 0, 64);
        const float thresh = s8 - MARGIN;
        int base = 0;
        #pragma unroll
        for (int j = 0; j < 4; ++j) {
            const bool c = (s0[j] >= thresh);
            const unsigned long long mk = __ballot(c);
            const int mypos = base + __popcll(mk & ((1ull << lane) - 1ull));
            if (c && mypos < 64) cand[(size_t)pos * 64 + mypos] = lane * 4 + j;
            base += (int)__popcll(mk);
        }
        if (lane == 0) { list[pos] = t; ncand[pos] = min(base, 64); }
    } else {
        const float inv = 1.f / (wsum + 1e-10f);
        if (lane < TOP_K) {
            out_idx[(size_t)t * TOP_K + lane] = (float)my_i;
            out_w[(size_t)t * TOP_K + lane] = my_g * inv;
        }
    }
}

// ---------------------------------------------------------------------------
// Kernel R: candidate-set f64 recheck.
// ---------------------------------------------------------------------------
__global__ __launch_bounds__(256) void recheck2(
    const float* __restrict__ H, const double* __restrict__ M64,
    const float* __restrict__ bias, const int* __restrict__ list,
    const int* __restrict__ ncand, const int* __restrict__ cand,
    const int* __restrict__ nmarg, float* __restrict__ out_idx,
    float* __restrict__ out_w)
{
    __shared__ float hsf[D_MODEL];
    __shared__ double sg[64], ssc[64];

    const int n = *nmarg;
    const int lane = threadIdx.x & 63, wv = threadIdx.x >> 6;

    for (int i = (int)blockIdx.x; i < n; i += (int)gridDim.x) {
        const int t = list[i];
        const int nc = ncand[i];

        for (int qd = threadIdx.x; qd < D_MODEL / 4; qd += 256)
            *(float4*)&hsf[qd * 4] = *(const float4*)(H + (size_t)t * D_MODEL + qd * 4);
        __syncthreads();

        for (int c = wv; c < nc; c += 4) {
            const int e = cand[(size_t)i * 64 + c];
            const double* mrow = M64 + (size_t)e * D_MODEL;
            double acc = 0.0;
            #pragma unroll 8
            for (int j = 0; j < 32; ++j) {
                const int k = lane + 64 * j;
                acc = fma((double)hsf[k], mrow[k], acc);
            }
            #pragma unroll
            for (int off = 1; off < 64; off <<= 1) acc += __shfl_xor(acc, off, 64);
            if (lane == 0) {
                const double gg = 1.0 / (1.0 + exp(-acc));
                sg[c] = gg;
                ssc[c] = gg + (double)bias[e];
            }
        }
        __syncthreads();

        if (wv == 0) {
            double s = -1e300, g = 0.0;
            int id = 1 << 20;
            if (lane < nc) { s = ssc[lane]; g = sg[lane]; id = cand[(size_t)i * 64 + lane]; }

            double wsum = 0.0, my_g = 0.0;
            int my_i = 0;
            for (int it = 0; it < TOP_K; ++it) {
                double bs = s, bg = g; int bi = id;
                #pragma unroll
                for (int off = 1; off < 64; off <<= 1) {
                    const double os = __shfl_xor(bs, off, 64);
                    const double og = __shfl_xor(bg, off, 64);
                    const int    oi = __shfl_xor(bi, off, 64);
                    if (os > bs || (os == bs && oi < bi)) { bs = os; bg = og; bi = oi; }
                }
                wsum += bg;
                if (lane == it) { my_i = bi; my_g = bg; }
                if (id == bi) s = -1e300;
            }
            const double inv = 1.0 / (wsum + 1e-10);
            if (lane < TOP_K) {
                out_idx[(size_t)t * TOP_K + lane] = (float)my_i;
                out_w[(size_t)t * TOP_K + lane] = (float)(my_g * inv);
            }
        }
        __syncthreads();
    }
}

// ---------------------------------------------------------------------------
// Kernel H: histogram out_idx -> counts; reduce csp[4096][256] -> sumP; the
// LAST block (ticket pattern) computes the balance loss. grid 64 x 256.
// ---------------------------------------------------------------------------
__global__ __launch_bounds__(256) void hist_reduce_loss(
    const float* __restrict__ out_idx, const float* __restrict__ csp,
    int* __restrict__ counts, double* __restrict__ sumP,
    int* __restrict__ done, float* __restrict__ out_loss)
{
    __shared__ int h[NUM_EXPERTS];
    __shared__ int ticket;
    const int tid = threadIdx.x;
    const int lane = tid & 63, wv = tid >> 6;
    h[tid] = 0;
    __syncthreads();
    for (int i = (int)blockIdx.x * 256 + tid; i < T_TOKENS * TOP_K; i += 64 * 256)
        atomicAdd(&h[(int)out_idx[i]], 1);
    __syncthreads();
    if (h[tid] != 0) atomicAdd(&counts[tid], h[tid]);

    const int e = (int)blockIdx.x * 4 + wv;
    float ps = 0.f;
    for (int p = lane; p < 4096; p += 64)
        ps += csp[(size_t)p * NUM_EXPERTS + e];
    #pragma unroll
    for (int off = 1; off < 64; off <<= 1) ps += __shfl_xor(ps, off, 64);
    if (lane == 0) sumP[e] = (double)ps;

    // last-block loss
    __threadfence();
    __syncthreads();
    if (tid == 0) ticket = atomicAdd(done, 1);
    __syncthreads();
    if (ticket == 63) {
        __shared__ double red[256];
        const int c = atomicAdd(&counts[tid], 0);          // coherent read
        const double sp = atomicAdd(&sumP[tid], 0.0);      // coherent read
        red[tid] = (double)c * sp;
        __syncthreads();
        #pragma unroll
        for (int sft = 128; sft > 0; sft >>= 1) {
            if (tid < sft) red[tid] += red[tid + sft];
            __syncthreads();
        }
        if (tid == 0) {
            const double denom = (double)T_TOKENS * (double)TOP_K * (double)T_TOKENS;
            out_loss[0] = (float)(0.001 * ((double)NUM_EXPERTS / (double)TOP_K) * red[0] / denom);
        }
    }
}

extern "C" void kernel_launch(void* const* d_in, const int* in_sizes, int n_in,
                              void* d_out, int out_size, void* d_ws, size_t ws_size,
                              hipStream_t stream) {
    (void)in_sizes; (void)n_in; (void)out_size; (void)ws_size;
    const float* hidden = (const float*)d_in[0];
    const float* W      = (const float*)d_in[1];
    const float* C      = (const float*)d_in[2];
    const float* bias   = (const float*)d_in[3];
    float* out = (float*)d_out;
    char* ws   = (char*)d_ws;

    double*         M64    = (double*)(ws + WS_M64_B);
    unsigned short* Mh     = (unsigned short*)(ws + WS_MH_B);
    unsigned short* Ml     = (unsigned short*)(ws + WS_ML_B);
    double*         sumP   = (double*)(ws + WS_SUMP_B);
    int*            counts = (int*)(ws + WS_CNT_B);
    int*            nmarg  = (int*)(ws + WS_NMARG_B);
    int*            done   = (int*)(ws + WS_NMARG_B) + 1;
    int*            list   = (int*)(ws + WS_LIST_B);
    int*            ncand  = (int*)(ws + WS_NCAND_B);
    int*            cand   = (int*)(ws + WS_CAND_B);
    float*          csp    = (float*)(ws + WS_CSP_B);
    double*         Mpart  = (double*)(ws + WS_MP_B);   // 16MB, dead after A2
    float*          paff1  = (float*)(ws + WS_MP_B);    // 16MB, alias (disjoint lifetime)

    hipMemsetAsync(ws + WS_CNT_B, 0, NUM_EXPERTS * 4 + 16, stream);

    cw_gemm_part<<<dim3(D_MODEL / 64, NUM_EXPERTS / 32, 4), 256, 0, stream>>>(C, W, Mpart);
    cw_combine<<<dim3(NUM_EXPERTS * D_MODEL / 1024), 256, 0, stream>>>(Mpart, M64, Mh, Ml);

    affinity_mfma<<<dim3(T_TOKENS / 64, 2, 2), 256, 0, stream>>>(
        hidden, Mh, Ml, out + OUT_AFF, paff1);

    topk_margin<<<dim3(T_TOKENS / 4), 256, 0, stream>>>(
        out + OUT_AFF, paff1, bias, out + OUT_AFF, csp,
        out + OUT_IDX, out + OUT_W, nmarg, list, ncand, cand);

    recheck2<<<dim3(2048), 256, 0, stream>>>(
        hidden, M64, bias, list, ncand, cand, nmarg, out + OUT_IDX, out + OUT_W);

    hist_reduce_loss<<<dim3(64), 256, 0, stream>>>(
        out + OUT_IDX, csp, counts, sumP, done, out + OUT_LOSS);
}

// Round 8
// 403.682 us; speedup vs baseline: 1.5744x; 1.1631x over previous
//
#include <hip/hip_runtime.h>
#include <math.h>

#define T_TOKENS    16384
#define D_MODEL     2048
#define NUM_EXPERTS 256
#define TOP_K       8
#define MARGIN      6e-5f

// d_out layout (floats): idx | weights | affinities | loss
#define OUT_IDX  0
#define OUT_W    (T_TOKENS * TOP_K)
#define OUT_AFF  (2 * T_TOKENS * TOP_K)
#define OUT_LOSS (2 * T_TOKENS * TOP_K + T_TOKENS * NUM_EXPERTS)

// ws layout (bytes)
#define WS_M64_B   ((size_t)0)                                    // double[256*2048] 4MB
#define WS_MH_B    (WS_M64_B + (size_t)NUM_EXPERTS * D_MODEL * 8) // bf16 1MB
#define WS_ML_B    (WS_MH_B  + (size_t)NUM_EXPERTS * D_MODEL * 2) // bf16 1MB
#define WS_SUMP_B  (WS_ML_B  + (size_t)NUM_EXPERTS * D_MODEL * 2) // double[256]
#define WS_CNT_B   (WS_SUMP_B + NUM_EXPERTS * 8)                  // int[256]
#define WS_NMARG_B (WS_CNT_B  + NUM_EXPERTS * 4)                  // int nmarg, int done (+pad)
#define WS_LIST_B  (WS_NMARG_B + 16)                              // int[16384] (unused)
#define WS_NCAND_B (WS_LIST_B + (size_t)T_TOKENS * 4)             // int[16384] (unused)
#define WS_CAND_B  (WS_NCAND_B + (size_t)T_TOKENS * 4)            // int[16384*64] 4MB (unused)
#define WS_CSP_B   (WS_CAND_B + (size_t)T_TOKENS * 64 * 4)        // float[2*256*128] 256KB (slot 4MB)
#define WS_MP_B    (WS_CSP_B + (size_t)4096 * 256 * 4)            // double[4][256*2048] 16MB

typedef __attribute__((ext_vector_type(8))) short short8;
typedef __attribute__((ext_vector_type(4))) float f32x4;

__device__ __forceinline__ unsigned short bf16_rne(float x) {
    unsigned u = __float_as_uint(x);
    u += 0x7FFFu + ((u >> 16) & 1u);
    return (unsigned short)(u >> 16);
}
__device__ __forceinline__ float bf16_f32(unsigned short h) {
    return __uint_as_float(((unsigned)h) << 16);
}
__device__ __forceinline__ unsigned ford(float f) {
    unsigned u = __float_as_uint(f);
    return ((int)u >= 0) ? (u | 0x80000000u) : ~u;
}
__device__ __forceinline__ float finv(unsigned o) {
    return (o & 0x80000000u) ? __uint_as_float(o ^ 0x80000000u)
                             : __uint_as_float(~o);
}
// async global->LDS, 16B per lane; LDS dest = wave-uniform base + lane*16
__device__ __forceinline__ void glds16(const void* g, void* l) {
    __builtin_amdgcn_global_load_lds(
        (const __attribute__((address_space(1))) unsigned int*)g,
        (__attribute__((address_space(3))) unsigned int*)l,
        16, 0, 0);
}

// ---------------------------------------------------------------------------
// Kernel A1: partial M = C @ W over a D-quarter — R4-EXACT VALU f64 version.
// (f64-MFMA variant reverted: its K-reassociation perturbs M64 by ~1 ulp and
// flips near-tie expert ordering vs. the reference — R7 failure.)
// tile 32e x 64k, grid (32,8,4) = 1024 blocks (4/CU).
// ---------------------------------------------------------------------------
__global__ __launch_bounds__(256, 4) void cw_gemm_part(
    const float* __restrict__ C, const float* __restrict__ W,
    double* __restrict__ Mpart)
{
    __shared__ float Cs[32][34];
    __shared__ float Ws[32][68];

    const int tid = threadIdx.x;
    const int tx = tid & 15;
    const int ty = tid >> 4;
    const int e0 = blockIdx.y * 32;
    const int k0 = blockIdx.x * 64;
    const int z  = blockIdx.z;

    double* Mp = Mpart + (size_t)z * NUM_EXPERTS * D_MODEL;
    double acc[2][4] = {{0,0,0,0},{0,0,0,0}};

    for (int d0 = z * 512; d0 < (z + 1) * 512; d0 += 32) {
        {
            const int e = tid >> 3, d4 = (tid & 7) * 4;
            const float4 v = *(const float4*)(C + (size_t)(e0 + e) * D_MODEL + d0 + d4);
            Cs[d4 + 0][e] = v.x; Cs[d4 + 1][e] = v.y;
            Cs[d4 + 2][e] = v.z; Cs[d4 + 3][e] = v.w;
        }
        #pragma unroll
        for (int r = 0; r < 2; ++r) {
            const int idx = tid + r * 256;
            const int d = idx >> 4, k4 = (idx & 15) * 4;
            *(float4*)&Ws[d][k4] =
                *(const float4*)(W + (size_t)(d0 + d) * D_MODEL + k0 + k4);
        }
        __syncthreads();
        #pragma unroll
        for (int dd = 0; dd < 32; ++dd) {
            const float2 a2 = *(const float2*)&Cs[dd][ty * 2];
            const double a0 = (double)a2.x, a1 = (double)a2.y;
            const float4 b4 = *(const float4*)&Ws[dd][tx * 4];
            const double b[4] = {(double)b4.x, (double)b4.y, (double)b4.z, (double)b4.w};
            #pragma unroll
            for (int j = 0; j < 4; ++j) { acc[0][j] += a0 * b[j]; acc[1][j] += a1 * b[j]; }
        }
        __syncthreads();
    }
    #pragma unroll
    for (int i = 0; i < 2; ++i) {
        const int e = e0 + ty * 2 + i;
        #pragma unroll
        for (int j = 0; j < 4; ++j)
            Mp[(size_t)e * D_MODEL + k0 + tx * 4 + j] = acc[i][j];
    }
}

// ---------------------------------------------------------------------------
// Kernel A2: combine 4 D-quarters -> M64, emit bf16 split Mh/Ml (row-major).
// grid 512x256. R4-exact.
// ---------------------------------------------------------------------------
__global__ __launch_bounds__(256) void cw_combine(
    const double* __restrict__ Mpart, double* __restrict__ M64,
    unsigned short* __restrict__ Mh, unsigned short* __restrict__ Ml)
{
    const int i4 = ((int)blockIdx.x * 256 + (int)threadIdx.x) * 4;
    const double* p0 = Mpart;
    const double* p1 = Mpart + (size_t)NUM_EXPERTS * D_MODEL;
    const double* p2 = Mpart + (size_t)2 * NUM_EXPERTS * D_MODEL;
    const double* p3 = Mpart + (size_t)3 * NUM_EXPERTS * D_MODEL;
    unsigned short hi[4], lo[4];
    #pragma unroll
    for (int u = 0; u < 4; ++u) {
        const double v = (p0[i4 + u] + p1[i4 + u]) + (p2[i4 + u] + p3[i4 + u]);
        M64[i4 + u] = v;
        const float f = (float)v;
        hi[u] = bf16_rne(f);
        lo[u] = bf16_rne(f - bf16_f32(hi[u]));
    }
    uint2 wh, wl;
    wh.x = (unsigned)hi[0] | ((unsigned)hi[1] << 16);
    wh.y = (unsigned)hi[2] | ((unsigned)hi[3] << 16);
    wl.x = (unsigned)lo[0] | ((unsigned)lo[1] << 16);
    wl.y = (unsigned)lo[2] | ((unsigned)lo[3] << 16);
    *(uint2*)(Mh + i4) = wh;
    *(uint2*)(Ml + i4) = wl;
}

// ---------------------------------------------------------------------------
// Kernel B: affinities via bf16-split MFMA — R4 EXACT (verified 115us).
// tile 64t x 128e, BK=64, grid (256,2) = 512 blocks, 64KB LDS -> 2 blocks/CU.
// Counted-in-flight pipeline: raw s_barrier + lgkmcnt(0) only; M-hi via
// wave-private global_load_lds; M-lo in registers (prefetch distance 2).
// ---------------------------------------------------------------------------
struct HRegs  { float4 a[2][2]; };   // [kk][half]
struct MlRegs { uint4  r[2][2]; };   // [j][kk]

__global__ __launch_bounds__(256, 2) void affinity_mfma(
    const float* __restrict__ H, const unsigned short* __restrict__ Mh,
    const unsigned short* __restrict__ Ml,
    float* __restrict__ aff, float* __restrict__ colsumPart)
{
    __shared__ unsigned short sHh[2][4096], sHl[2][4096];
    __shared__ unsigned short sMh[2][8192];

    const int tid = threadIdx.x;
    const int lane = tid & 63, wv = tid >> 6;
    const int m = lane & 15, quad = lane >> 4;
    const int t0 = (int)blockIdx.x * 64;
    const int e0 = (int)blockIdx.y * 128;

    const int grp = tid >> 6;
    const int q   = (tid >> 4) & 3;
    const int m16 = tid & 15;

    f32x4 acc[4][2];
    #pragma unroll
    for (int i = 0; i < 4; ++i)
        #pragma unroll
        for (int j = 0; j < 2; ++j) acc[i][j] = (f32x4){0.f, 0.f, 0.f, 0.f};

    HRegs RA, RB;
    MlRegs RLA, RLB;

    auto loadH = [&](int kc, HRegs& R) {
        const float* hp = H + (size_t)(t0 + grp * 16 + m16) * D_MODEL + kc * 64 + q * 8;
        #pragma unroll
        for (int kk = 0; kk < 2; ++kk) {
            R.a[kk][0] = *(const float4*)(hp + kk * 32);
            R.a[kk][1] = *(const float4*)(hp + kk * 32 + 4);
        }
    };
    auto loadMl = [&](int kc, MlRegs& R) {
        #pragma unroll
        for (int j = 0; j < 2; ++j) {
            const unsigned short* mp =
                Ml + (size_t)(e0 + (wv * 2 + j) * 16 + m) * D_MODEL + kc * 64 + quad * 8;
            #pragma unroll
            for (int kk = 0; kk < 2; ++kk)
                R.r[j][kk] = *(const uint4*)(mp + kk * 32);
        }
    };
    auto stageH = [&](int b, const HRegs& R) {
        #pragma unroll
        for (int kk = 0; kk < 2; ++kk) {
            const float4 A = R.a[kk][0], B = R.a[kk][1];
            float x[8] = {A.x, A.y, A.z, A.w, B.x, B.y, B.z, B.w};
            unsigned short hi[8], lo[8];
            #pragma unroll
            for (int u = 0; u < 8; ++u) {
                hi[u] = bf16_rne(x[u]);
                lo[u] = bf16_rne(x[u] - bf16_f32(hi[u]));
            }
            uint4 ph, pl;
            ph.x = (unsigned)hi[0] | ((unsigned)hi[1] << 16);
            ph.y = (unsigned)hi[2] | ((unsigned)hi[3] << 16);
            ph.z = (unsigned)hi[4] | ((unsigned)hi[5] << 16);
            ph.w = (unsigned)hi[6] | ((unsigned)hi[7] << 16);
            pl.x = (unsigned)lo[0] | ((unsigned)lo[1] << 16);
            pl.y = (unsigned)lo[2] | ((unsigned)lo[3] << 16);
            pl.z = (unsigned)lo[4] | ((unsigned)lo[5] << 16);
            pl.w = (unsigned)lo[6] | ((unsigned)lo[7] << 16);
            *(uint4*)&sHh[b][kk * 2048 + grp * 512 + lane * 8] = ph;
            *(uint4*)&sHl[b][kk * 2048 + grp * 512 + lane * 8] = pl;
        }
    };
    auto gldsM = [&](int kc, int b) {
        #pragma unroll
        for (int s = 0; s < 2; ++s) {
            const unsigned short* mp =
                Mh + (size_t)(e0 + (grp * 2 + s) * 16 + m16) * D_MODEL + kc * 64 + q * 8;
            #pragma unroll
            for (int kk = 0; kk < 2; ++kk)
                glds16(mp + kk * 32, &sMh[b][kk * 4096 + (grp * 2 + s) * 512]);
        }
    };
    auto mfmaT = [&](int b, const MlRegs& RL) {
        #pragma unroll
        for (int kk = 0; kk < 2; ++kk) {
            short8 ah[4], al[4], bh[2], bl[2];
            #pragma unroll
            for (int i = 0; i < 4; ++i) {
                ah[i] = *(const short8*)&sHh[b][kk * 2048 + i * 512 + lane * 8];
                al[i] = *(const short8*)&sHl[b][kk * 2048 + i * 512 + lane * 8];
            }
            #pragma unroll
            for (int j = 0; j < 2; ++j) {
                bh[j] = *(const short8*)&sMh[b][kk * 4096 + (wv * 2 + j) * 512 + lane * 8];
                bl[j] = *(const short8*)&RL.r[j][kk];
            }
            __builtin_amdgcn_s_setprio(1);
            #pragma unroll
            for (int i = 0; i < 4; ++i)
                #pragma unroll
                for (int j = 0; j < 2; ++j) {
                    acc[i][j] = __builtin_amdgcn_mfma_f32_16x16x32_bf16(ah[i], bh[j], acc[i][j], 0, 0, 0);
                    acc[i][j] = __builtin_amdgcn_mfma_f32_16x16x32_bf16(ah[i], bl[j], acc[i][j], 0, 0, 0);
                    acc[i][j] = __builtin_amdgcn_mfma_f32_16x16x32_bf16(al[i], bh[j], acc[i][j], 0, 0, 0);
                }
            __builtin_amdgcn_s_setprio(0);
        }
    };

    gldsM(0, 0);
    gldsM(1, 1);
    loadH(0, RA);
    loadH(1, RB);
    loadMl(0, RLA);
    loadMl(1, RLB);
    stageH(0, RA);
    asm volatile("s_waitcnt lgkmcnt(0)" ::: "memory");
    __builtin_amdgcn_s_barrier();

    for (int k = 0; k < 32; k += 2) {
        stageH(1, RB);
        if (k + 2 < 32) loadH(k + 2, RA);
        mfmaT(0, RLA);
        if (k + 2 < 32) loadMl(k + 2, RLA);
        if (k + 2 < 32) gldsM(k + 2, 0);
        asm volatile("s_waitcnt lgkmcnt(0)" ::: "memory");
        __builtin_amdgcn_s_barrier();

        if (k + 2 < 32) {
            stageH(0, RA);
        } else {
            asm volatile("s_waitcnt vmcnt(0)" ::: "memory");
        }
        if (k + 3 < 32) loadH(k + 3, RB);
        mfmaT(1, RLB);
        if (k + 3 < 32) loadMl(k + 3, RLB);
        if (k + 3 < 32) gldsM(k + 3, 1);
        asm volatile("s_waitcnt lgkmcnt(0)" ::: "memory");
        __builtin_amdgcn_s_barrier();
    }

    #pragma unroll
    for (int j = 0; j < 2; ++j) {
        const int el = wv * 32 + j * 16 + m;
        const int e = e0 + el;
        float colsum = 0.f;
        #pragma unroll
        for (int i = 0; i < 4; ++i) {
            const int tbase = t0 + i * 16 + quad * 4;
            #pragma unroll
            for (int r = 0; r < 4; ++r) {
                const float v = acc[i][j][r];
                aff[(size_t)(tbase + r) * NUM_EXPERTS + e] = v;
                colsum += 1.f / (1.f + expf(-v));
            }
        }
        colsum += __shfl_xor(colsum, 16, 64);
        colsum += __shfl_xor(colsum, 32, 64);
        if (quad == 0)
            colsumPart[((size_t)blockIdx.y * 256 + blockIdx.x) * 128 + el] = colsum;
    }
}

// ---------------------------------------------------------------------------
// Kernel C: fused top-9 + margin test + INLINE f64 recheck (per-wave).
// grid 4096 x 256 (4 tokens/block). No inter-wave sync; within-wave LDS
// ordering via lgkmcnt(0). Arithmetic identical to the verified split pair.
// ---------------------------------------------------------------------------
__global__ __launch_bounds__(256) void topk_recheck(
    const float* __restrict__ aff, const float* __restrict__ bias,
    const float* __restrict__ H, const double* __restrict__ M64,
    float* __restrict__ out_idx, float* __restrict__ out_w)
{
    __shared__ float  hs[4][D_MODEL];     // 32KB
    __shared__ int    scand[4][64];       // 1KB
    __shared__ double sgd[4][64];         // 2KB
    __shared__ double ssd[4][64];         // 2KB

    const int lane = threadIdx.x & 63;
    const int wv = threadIdx.x >> 6;
    const int t = blockIdx.x * 4 + wv;

    const float4 av = *(const float4*)(aff + (size_t)t * NUM_EXPERTS + lane * 4);
    const float4 bv = *(const float4*)(bias + lane * 4);
    float g[4], s0[4];
    g[0] = 1.f / (1.f + expf(-av.x)); s0[0] = g[0] + bv.x;
    g[1] = 1.f / (1.f + expf(-av.y)); s0[1] = g[1] + bv.y;
    g[2] = 1.f / (1.f + expf(-av.z)); s0[2] = g[2] + bv.z;
    g[3] = 1.f / (1.f + expf(-av.w)); s0[3] = g[3] + bv.w;

    unsigned long long kw[4];
    #pragma unroll
    for (int j = 0; j < 4; ++j)
        kw[j] = ((unsigned long long)ford(s0[j]) << 32)
              | (unsigned long long)(0xFFFFFFFFu - (unsigned)(lane * 4 + j));

    float wsum = 0.f, my_g = 0.f, prevs = 0.f, minGap = 1e30f, s8 = 0.f;
    int my_i = 0;

    #pragma unroll
    for (int it = 0; it < 9; ++it) {
        unsigned long long bk = kw[0];
        if (kw[1] > bk) bk = kw[1];
        if (kw[2] > bk) bk = kw[2];
        if (kw[3] > bk) bk = kw[3];
        #pragma unroll
        for (int off = 1; off < 64; off <<= 1) {
            const unsigned long long ok = __shfl_xor(bk, off, 64);
            if (ok > bk) bk = ok;
        }
        const unsigned o = (unsigned)(bk >> 32);
        const float sv = finv(o);
        const int e = (int)(0xFFFFFFFFu - (unsigned)(bk & 0xFFFFFFFFu));
        const int ej = e & 3, el = e >> 2;
        const float gl = (ej == 0) ? g[0] : (ej == 1) ? g[1] : (ej == 2) ? g[2] : g[3];
        const float gv = __shfl(gl, el, 64);
        if (it < TOP_K) {
            wsum += gv;
            if (lane == it) { my_i = e; my_g = gv; }
            if (it == 7) s8 = sv;
        }
        if (it > 0) minGap = fminf(minGap, prevs - sv);
        prevs = sv;
        if (lane == el) {
            if (ej == 0) kw[0] = 0ull; else if (ej == 1) kw[1] = 0ull;
            else if (ej == 2) kw[2] = 0ull; else kw[3] = 0ull;
        }
    }

    if (minGap < MARGIN) {
        // ---- inline f64 recheck for this wave's token ----
        const float thresh = s8 - MARGIN;
        int base = 0;
        #pragma unroll
        for (int j = 0; j < 4; ++j) {
            const bool c = (s0[j] >= thresh);
            const unsigned long long mk = __ballot(c);
            const int mypos = base + __popcll(mk & ((1ull << lane) - 1ull));
            if (c && mypos < 64) scand[wv][mypos] = lane * 4 + j;
            base += (int)__popcll(mk);
        }
        const int nc = min(base, 64);
        #pragma unroll
        for (int jj = 0; jj < 8; ++jj) {
            const int d4 = (jj * 64 + lane) * 4;
            *(float4*)&hs[wv][d4] = *(const float4*)(H + (size_t)t * D_MODEL + d4);
        }
        asm volatile("s_waitcnt lgkmcnt(0)" ::: "memory");  // wave-local LDS ready

        for (int c = 0; c < nc; ++c) {
            const int e = scand[wv][c];
            const double* mrow = M64 + (size_t)e * D_MODEL;
            double acc = 0.0;
            #pragma unroll 8
            for (int j = 0; j < 32; ++j) {
                const int k = lane + 64 * j;
                acc = fma((double)hs[wv][k], mrow[k], acc);
            }
            #pragma unroll
            for (int off = 1; off < 64; off <<= 1) acc += __shfl_xor(acc, off, 64);
            if (lane == 0) {
                const double gg = 1.0 / (1.0 + exp(-acc));
                sgd[wv][c] = gg;
                ssd[wv][c] = gg + (double)bias[e];
            }
        }
        asm volatile("s_waitcnt lgkmcnt(0)" ::: "memory");

        double s = -1e300, gd = 0.0;
        int id = 1 << 20;
        if (lane < nc) { s = ssd[wv][lane]; gd = sgd[wv][lane]; id = scand[wv][lane]; }

        double wsum2 = 0.0, my_g2 = 0.0;
        int my_i2 = 0;
        for (int it = 0; it < TOP_K; ++it) {
            double bs = s, bg = gd; int bi = id;
            #pragma unroll
            for (int off = 1; off < 64; off <<= 1) {
                const double os = __shfl_xor(bs, off, 64);
                const double og = __shfl_xor(bg, off, 64);
                const int    oi = __shfl_xor(bi, off, 64);
                if (os > bs || (os == bs && oi < bi)) { bs = os; bg = og; bi = oi; }
            }
            wsum2 += bg;
            if (lane == it) { my_i2 = bi; my_g2 = bg; }
            if (id == bi) s = -1e300;
        }
        const double inv = 1.0 / (wsum2 + 1e-10);
        if (lane < TOP_K) {
            out_idx[(size_t)t * TOP_K + lane] = (float)my_i2;
            out_w[(size_t)t * TOP_K + lane] = (float)(my_g2 * inv);
        }
    } else {
        const float inv = 1.f / (wsum + 1e-10f);
        if (lane < TOP_K) {
            out_idx[(size_t)t * TOP_K + lane] = (float)my_i;
            out_w[(size_t)t * TOP_K + lane] = my_g * inv;
        }
    }
}

// ---------------------------------------------------------------------------
// Kernel H: histogram out_idx -> counts; reduce colsumPart -> sumP; the
// LAST block (ticket pattern) computes the balance loss. grid 64 x 256.
// colsumPart is [2][256][128]. R4-exact.
// ---------------------------------------------------------------------------
__global__ __launch_bounds__(256) void hist_reduce_loss(
    const float* __restrict__ out_idx, const float* __restrict__ colsumPart,
    int* __restrict__ counts, double* __restrict__ sumP,
    int* __restrict__ done, float* __restrict__ out_loss)
{
    __shared__ int h[NUM_EXPERTS];
    __shared__ int ticket;
    const int tid = threadIdx.x;
    const int lane = tid & 63, wv = tid >> 6;
    h[tid] = 0;
    __syncthreads();
    for (int i = (int)blockIdx.x * 256 + tid; i < T_TOKENS * TOP_K; i += 64 * 256)
        atomicAdd(&h[(int)out_idx[i]], 1);
    __syncthreads();
    if (h[tid] != 0) atomicAdd(&counts[tid], h[tid]);

    const int e = (int)blockIdx.x * 4 + wv;
    const int half = e >> 7, el = e & 127;
    float ps = 0.f;
    for (int p = lane; p < 256; p += 64)
        ps += colsumPart[((size_t)half * 256 + p) * 128 + el];
    #pragma unroll
    for (int off = 1; off < 64; off <<= 1) ps += __shfl_xor(ps, off, 64);
    if (lane == 0) sumP[e] = (double)ps;

    __threadfence();
    __syncthreads();
    if (tid == 0) ticket = atomicAdd(done, 1);
    __syncthreads();
    if (ticket == 63) {
        __shared__ double red[256];
        const int c = atomicAdd(&counts[tid], 0);
        const double sp = atomicAdd(&sumP[tid], 0.0);
        red[tid] = (double)c * sp;
        __syncthreads();
        #pragma unroll
        for (int sft = 128; sft > 0; sft >>= 1) {
            if (tid < sft) red[tid] += red[tid + sft];
            __syncthreads();
        }
        if (tid == 0) {
            const double denom = (double)T_TOKENS * (double)TOP_K * (double)T_TOKENS;
            out_loss[0] = (float)(0.001 * ((double)NUM_EXPERTS / (double)TOP_K) * red[0] / denom);
        }
    }
}

extern "C" void kernel_launch(void* const* d_in, const int* in_sizes, int n_in,
                              void* d_out, int out_size, void* d_ws, size_t ws_size,
                              hipStream_t stream) {
    (void)in_sizes; (void)n_in; (void)out_size; (void)ws_size;
    const float* hidden = (const float*)d_in[0];
    const float* W      = (const float*)d_in[1];
    const float* C      = (const float*)d_in[2];
    const float* bias   = (const float*)d_in[3];
    float* out = (float*)d_out;
    char* ws   = (char*)d_ws;

    double*         M64    = (double*)(ws + WS_M64_B);
    unsigned short* Mh     = (unsigned short*)(ws + WS_MH_B);
    unsigned short* Ml     = (unsigned short*)(ws + WS_ML_B);
    double*         sumP   = (double*)(ws + WS_SUMP_B);
    int*            counts = (int*)(ws + WS_CNT_B);
    int*            done   = (int*)(ws + WS_NMARG_B) + 1;
    float*          csp    = (float*)(ws + WS_CSP_B);
    double*         Mpart  = (double*)(ws + WS_MP_B);

    hipMemsetAsync(ws + WS_CNT_B, 0, NUM_EXPERTS * 4 + 16, stream);

    cw_gemm_part<<<dim3(D_MODEL / 64, NUM_EXPERTS / 32, 4), 256, 0, stream>>>(C, W, Mpart);
    cw_combine<<<dim3(NUM_EXPERTS * D_MODEL / 1024), 256, 0, stream>>>(Mpart, M64, Mh, Ml);

    affinity_mfma<<<dim3(T_TOKENS / 64, 2), 256, 0, stream>>>(hidden, Mh, Ml, out + OUT_AFF, csp);

    topk_recheck<<<dim3(T_TOKENS / 4), 256, 0, stream>>>(
        out + OUT_AFF, bias, hidden, M64, out + OUT_IDX, out + OUT_W);

    hist_reduce_loss<<<dim3(64), 256, 0, stream>>>(
        out + OUT_IDX, csp, counts, sumP, done, out + OUT_LOSS);
}

// Round 9
// 402.100 us; speedup vs baseline: 1.5806x; 1.0039x over previous
//
#include <hip/hip_runtime.h>
#include <math.h>

#define T_TOKENS    16384
#define D_MODEL     2048
#define NUM_EXPERTS 256
#define TOP_K       8
#define MARGIN      6e-5f

// d_out layout (floats): idx | weights | affinities | loss
#define OUT_IDX  0
#define OUT_W    (T_TOKENS * TOP_K)
#define OUT_AFF  (2 * T_TOKENS * TOP_K)
#define OUT_LOSS (2 * T_TOKENS * TOP_K + T_TOKENS * NUM_EXPERTS)

// ws layout (bytes)
#define WS_M64_B   ((size_t)0)                                    // double[256*2048] 4MB
#define WS_MH_B    (WS_M64_B + (size_t)NUM_EXPERTS * D_MODEL * 8) // bf16 1MB
#define WS_ML_B    (WS_MH_B  + (size_t)NUM_EXPERTS * D_MODEL * 2) // bf16 1MB
#define WS_SUMP_B  (WS_ML_B  + (size_t)NUM_EXPERTS * D_MODEL * 2) // double[256]
#define WS_CNT_B   (WS_SUMP_B + NUM_EXPERTS * 8)                  // int[256]
#define WS_NMARG_B (WS_CNT_B  + NUM_EXPERTS * 4)                  // int nmarg, int done (+pad)
#define WS_LIST_B  (WS_NMARG_B + 16)                              // int[16384]
#define WS_NCAND_B (WS_LIST_B + (size_t)T_TOKENS * 4)             // int[16384]
#define WS_CAND_B  (WS_NCAND_B + (size_t)T_TOKENS * 4)            // int[16384*64] 4MB
#define WS_CSP_B   (WS_CAND_B + (size_t)T_TOKENS * 64 * 4)        // float[2*256*128] 256KB (slot 4MB)
#define WS_MP_B    (WS_CSP_B + (size_t)4096 * 256 * 4)            // double[4][256*2048] 16MB

typedef __attribute__((ext_vector_type(8))) short short8;
typedef __attribute__((ext_vector_type(4))) float f32x4;

__device__ __forceinline__ unsigned short bf16_rne(float x) {
    unsigned u = __float_as_uint(x);
    u += 0x7FFFu + ((u >> 16) & 1u);
    return (unsigned short)(u >> 16);
}
__device__ __forceinline__ float bf16_f32(unsigned short h) {
    return __uint_as_float(((unsigned)h) << 16);
}
__device__ __forceinline__ unsigned ford(float f) {
    unsigned u = __float_as_uint(f);
    return ((int)u >= 0) ? (u | 0x80000000u) : ~u;
}
__device__ __forceinline__ float finv(unsigned o) {
    return (o & 0x80000000u) ? __uint_as_float(o ^ 0x80000000u)
                             : __uint_as_float(~o);
}
// async global->LDS, 16B per lane; LDS dest = wave-uniform base + lane*16
__device__ __forceinline__ void glds16(const void* g, void* l) {
    __builtin_amdgcn_global_load_lds(
        (const __attribute__((address_space(1))) unsigned int*)g,
        (__attribute__((address_space(3))) unsigned int*)l,
        16, 0, 0);
}

// ---------------------------------------------------------------------------
// Kernel A1: partial M = C @ W over a D-quarter — R4-EXACT VALU f64 version
// (bit-exact M64 chain is load-bearing for near-tie resolution; R7 lesson).
// tile 32e x 64k, grid (32,8,4) = 1024 blocks (4/CU).
// ---------------------------------------------------------------------------
__global__ __launch_bounds__(256, 4) void cw_gemm_part(
    const float* __restrict__ C, const float* __restrict__ W,
    double* __restrict__ Mpart)
{
    __shared__ float Cs[32][34];
    __shared__ float Ws[32][68];

    const int tid = threadIdx.x;
    const int tx = tid & 15;
    const int ty = tid >> 4;
    const int e0 = blockIdx.y * 32;
    const int k0 = blockIdx.x * 64;
    const int z  = blockIdx.z;

    double* Mp = Mpart + (size_t)z * NUM_EXPERTS * D_MODEL;
    double acc[2][4] = {{0,0,0,0},{0,0,0,0}};

    for (int d0 = z * 512; d0 < (z + 1) * 512; d0 += 32) {
        {
            const int e = tid >> 3, d4 = (tid & 7) * 4;
            const float4 v = *(const float4*)(C + (size_t)(e0 + e) * D_MODEL + d0 + d4);
            Cs[d4 + 0][e] = v.x; Cs[d4 + 1][e] = v.y;
            Cs[d4 + 2][e] = v.z; Cs[d4 + 3][e] = v.w;
        }
        #pragma unroll
        for (int r = 0; r < 2; ++r) {
            const int idx = tid + r * 256;
            const int d = idx >> 4, k4 = (idx & 15) * 4;
            *(float4*)&Ws[d][k4] =
                *(const float4*)(W + (size_t)(d0 + d) * D_MODEL + k0 + k4);
        }
        __syncthreads();
        #pragma unroll
        for (int dd = 0; dd < 32; ++dd) {
            const float2 a2 = *(const float2*)&Cs[dd][ty * 2];
            const double a0 = (double)a2.x, a1 = (double)a2.y;
            const float4 b4 = *(const float4*)&Ws[dd][tx * 4];
            const double b[4] = {(double)b4.x, (double)b4.y, (double)b4.z, (double)b4.w};
            #pragma unroll
            for (int j = 0; j < 4; ++j) { acc[0][j] += a0 * b[j]; acc[1][j] += a1 * b[j]; }
        }
        __syncthreads();
    }
    #pragma unroll
    for (int i = 0; i < 2; ++i) {
        const int e = e0 + ty * 2 + i;
        #pragma unroll
        for (int j = 0; j < 4; ++j)
            Mp[(size_t)e * D_MODEL + k0 + tx * 4 + j] = acc[i][j];
    }
}

// ---------------------------------------------------------------------------
// Kernel A2: combine 4 D-quarters -> M64, emit bf16 split Mh/Ml (row-major).
// grid 512x256. R4-exact.
// ---------------------------------------------------------------------------
__global__ __launch_bounds__(256) void cw_combine(
    const double* __restrict__ Mpart, double* __restrict__ M64,
    unsigned short* __restrict__ Mh, unsigned short* __restrict__ Ml)
{
    const int i4 = ((int)blockIdx.x * 256 + (int)threadIdx.x) * 4;
    const double* p0 = Mpart;
    const double* p1 = Mpart + (size_t)NUM_EXPERTS * D_MODEL;
    const double* p2 = Mpart + (size_t)2 * NUM_EXPERTS * D_MODEL;
    const double* p3 = Mpart + (size_t)3 * NUM_EXPERTS * D_MODEL;
    unsigned short hi[4], lo[4];
    #pragma unroll
    for (int u = 0; u < 4; ++u) {
        const double v = (p0[i4 + u] + p1[i4 + u]) + (p2[i4 + u] + p3[i4 + u]);
        M64[i4 + u] = v;
        const float f = (float)v;
        hi[u] = bf16_rne(f);
        lo[u] = bf16_rne(f - bf16_f32(hi[u]));
    }
    uint2 wh, wl;
    wh.x = (unsigned)hi[0] | ((unsigned)hi[1] << 16);
    wh.y = (unsigned)hi[2] | ((unsigned)hi[3] << 16);
    wl.x = (unsigned)lo[0] | ((unsigned)lo[1] << 16);
    wl.y = (unsigned)lo[2] | ((unsigned)lo[3] << 16);
    *(uint2*)(Mh + i4) = wh;
    *(uint2*)(Ml + i4) = wl;
}

// ---------------------------------------------------------------------------
// Kernel B: affinities via bf16-split MFMA — 8-WAVE WIDE variant of R4.
// Same 64t x 128e tile, BK=64, grid (256,2) = 512 blocks, but 512 threads:
// 2 blocks/CU x 8 waves = 16 waves/CU (R4: 8). Per-CU MFMA density per
// barrier period is conserved (each wave owns ONE e-tile: acc[4], 24
// MFMA/chunk). Waves 0-3 stage H (shared); every wave glds its own
// wave-private Mh tile and keeps Ml in regs (prefetch distance 2).
// Ledger fix vs R4: gldsM is issued BEFORE loadMl in each body, so
// mfmaT's register wait on Ml retires the older glds for ALL waves
// (waves 4-7 have no stageH wait). Operands & MFMA order bit-identical.
// ---------------------------------------------------------------------------
struct HRegs  { float4 a[2][2]; };   // [kk][half]
struct MlRegs { uint4  r[2]; };      // [kk]

__global__ __launch_bounds__(512, 4) void affinity_mfma(
    const float* __restrict__ H, const unsigned short* __restrict__ Mh,
    const unsigned short* __restrict__ Ml,
    float* __restrict__ aff, float* __restrict__ colsumPart)
{
    __shared__ unsigned short sHh[2][4096], sHl[2][4096];   // 16KB + 16KB
    __shared__ unsigned short sMh[2][8192];                 // 32KB

    const int tid = threadIdx.x;
    const int lane = tid & 63, wv = tid >> 6;   // wv in 0..7
    const int m = lane & 15, quad = lane >> 4;
    const int t0 = (int)blockIdx.x * 64;
    const int e0 = (int)blockIdx.y * 128;

    f32x4 acc[4];
    #pragma unroll
    for (int i = 0; i < 4; ++i) acc[i] = (f32x4){0.f, 0.f, 0.f, 0.f};

    HRegs RA, RB;        // H prefetch (waves 0-3 only)
    MlRegs RLA, RLB;     // Ml prefetch (all waves)

    auto loadH = [&](int kc, HRegs& R) {
        if (wv < 4) {
            const float* hp = H + (size_t)(t0 + wv * 16 + m) * D_MODEL + kc * 64 + quad * 8;
            #pragma unroll
            for (int kk = 0; kk < 2; ++kk) {
                R.a[kk][0] = *(const float4*)(hp + kk * 32);
                R.a[kk][1] = *(const float4*)(hp + kk * 32 + 4);
            }
        }
    };
    auto loadMl = [&](int kc, MlRegs& R) {
        const unsigned short* mp =
            Ml + (size_t)(e0 + wv * 16 + m) * D_MODEL + kc * 64 + quad * 8;
        #pragma unroll
        for (int kk = 0; kk < 2; ++kk)
            R.r[kk] = *(const uint4*)(mp + kk * 32);
    };
    auto stageH = [&](int b, const HRegs& R) {
        if (wv < 4) {
            #pragma unroll
            for (int kk = 0; kk < 2; ++kk) {
                const float4 A = R.a[kk][0], B = R.a[kk][1];
                float x[8] = {A.x, A.y, A.z, A.w, B.x, B.y, B.z, B.w};
                unsigned short hi[8], lo[8];
                #pragma unroll
                for (int u = 0; u < 8; ++u) {
                    hi[u] = bf16_rne(x[u]);
                    lo[u] = bf16_rne(x[u] - bf16_f32(hi[u]));
                }
                uint4 ph, pl;
                ph.x = (unsigned)hi[0] | ((unsigned)hi[1] << 16);
                ph.y = (unsigned)hi[2] | ((unsigned)hi[3] << 16);
                ph.z = (unsigned)hi[4] | ((unsigned)hi[5] << 16);
                ph.w = (unsigned)hi[6] | ((unsigned)hi[7] << 16);
                pl.x = (unsigned)lo[0] | ((unsigned)lo[1] << 16);
                pl.y = (unsigned)lo[2] | ((unsigned)lo[3] << 16);
                pl.z = (unsigned)lo[4] | ((unsigned)lo[5] << 16);
                pl.w = (unsigned)lo[6] | ((unsigned)lo[7] << 16);
                *(uint4*)&sHh[b][kk * 2048 + wv * 512 + lane * 8] = ph;
                *(uint4*)&sHl[b][kk * 2048 + wv * 512 + lane * 8] = pl;
            }
        }
    };
    auto gldsM = [&](int kc, int b) {
        const unsigned short* mp =
            Mh + (size_t)(e0 + wv * 16 + m) * D_MODEL + kc * 64 + quad * 8;
        #pragma unroll
        for (int kk = 0; kk < 2; ++kk)
            glds16(mp + kk * 32, &sMh[b][kk * 4096 + wv * 512]);
    };
    auto mfmaT = [&](int b, const MlRegs& RL) {
        #pragma unroll
        for (int kk = 0; kk < 2; ++kk) {
            short8 ah[4], al[4];
            #pragma unroll
            for (int i = 0; i < 4; ++i) {
                ah[i] = *(const short8*)&sHh[b][kk * 2048 + i * 512 + lane * 8];
                al[i] = *(const short8*)&sHl[b][kk * 2048 + i * 512 + lane * 8];
            }
            const short8 bh = *(const short8*)&sMh[b][kk * 4096 + wv * 512 + lane * 8];
            const short8 bl = *(const short8*)&RL.r[kk];
            __builtin_amdgcn_s_setprio(1);
            #pragma unroll
            for (int i = 0; i < 4; ++i) {
                acc[i] = __builtin_amdgcn_mfma_f32_16x16x32_bf16(ah[i], bh, acc[i], 0, 0, 0);
                acc[i] = __builtin_amdgcn_mfma_f32_16x16x32_bf16(ah[i], bl, acc[i], 0, 0, 0);
                acc[i] = __builtin_amdgcn_mfma_f32_16x16x32_bf16(al[i], bh, acc[i], 0, 0, 0);
            }
            __builtin_amdgcn_s_setprio(0);
        }
    };

    // prologue: glds BEFORE register loads -> any register-load wait
    // retires the older glds (all waves).
    gldsM(0, 0);
    gldsM(1, 1);
    loadH(0, RA);
    loadH(1, RB);
    loadMl(0, RLA);
    loadMl(1, RLB);
    stageH(0, RA);
    asm volatile("s_waitcnt lgkmcnt(0)" ::: "memory");
    __builtin_amdgcn_s_barrier();                   // chunk0 ready

    for (int k = 0; k < 32; k += 2) {
        // ---- even body: compute chunk k from buf0 ----
        stageH(1, RB);                              // w<4: waits LH(k+1), retires GM(k)
        loadH(k + 2 < 32 ? k + 2 : 0, RA);          // LH(k+2) (guarded inside)
        mfmaT(0, RLA);                              // waits RLA=ML(k) -> retires GM(k) for all
        if (k + 2 < 32) {
            gldsM(k + 2, 0);                        // GM(k+2) BEFORE ML(k+2)
            loadMl(k + 2, RLA);
        }
        asm volatile("s_waitcnt lgkmcnt(0)" ::: "memory");
        __builtin_amdgcn_s_barrier();               // chunk k+1 H ready

        // ---- odd body: compute chunk k+1 from buf1 ----
        if (k + 2 < 32) {
            stageH(0, RA);
        } else {
            asm volatile("s_waitcnt vmcnt(0)" ::: "memory");  // defensive tail drain
        }
        if (k + 3 < 32) loadH(k + 3, RB);
        mfmaT(1, RLB);                              // waits RLB=ML(k+1) -> retires GM(k+1)
        if (k + 3 < 32) {
            gldsM(k + 3, 1);
            loadMl(k + 3, RLB);
        }
        asm volatile("s_waitcnt lgkmcnt(0)" ::: "memory");
        __builtin_amdgcn_s_barrier();               // chunk k+2 H ready
    }

    // epilogue: aff stores + sigmoid column partial sums (no atomics)
    {
        const int el = wv * 16 + m;            // local expert in [0,128)
        const int e = e0 + el;
        float colsum = 0.f;
        #pragma unroll
        for (int i = 0; i < 4; ++i) {
            const int tbase = t0 + i * 16 + quad * 4;
            #pragma unroll
            for (int r = 0; r < 4; ++r) {
                const float v = acc[i][r];
                aff[(size_t)(tbase + r) * NUM_EXPERTS + e] = v;
                colsum += 1.f / (1.f + expf(-v));
            }
        }
        colsum += __shfl_xor(colsum, 16, 64);
        colsum += __shfl_xor(colsum, 32, 64);
        if (quad == 0)
            colsumPart[((size_t)blockIdx.y * 256 + blockIdx.x) * 128 + el] = colsum;
    }
}

// ---------------------------------------------------------------------------
// Kernel C: fast top-9 (f32) on packed u64 keys + margin test. R4-exact.
// ---------------------------------------------------------------------------
__global__ __launch_bounds__(256) void topk_margin(
    const float* __restrict__ aff, const float* __restrict__ bias,
    float* __restrict__ out_idx, float* __restrict__ out_w,
    int* __restrict__ nmarg, int* __restrict__ list,
    int* __restrict__ ncand, int* __restrict__ cand)
{
    const int lane = threadIdx.x & 63;
    const int wv = threadIdx.x >> 6;
    const int t = blockIdx.x * 4 + wv;

    const float4 av = *(const float4*)(aff + (size_t)t * NUM_EXPERTS + lane * 4);
    const float4 bv = *(const float4*)(bias + lane * 4);
    float g[4], s0[4];
    g[0] = 1.f / (1.f + expf(-av.x)); s0[0] = g[0] + bv.x;
    g[1] = 1.f / (1.f + expf(-av.y)); s0[1] = g[1] + bv.y;
    g[2] = 1.f / (1.f + expf(-av.z)); s0[2] = g[2] + bv.z;
    g[3] = 1.f / (1.f + expf(-av.w)); s0[3] = g[3] + bv.w;

    unsigned long long kw[4];
    #pragma unroll
    for (int j = 0; j < 4; ++j)
        kw[j] = ((unsigned long long)ford(s0[j]) << 32)
              | (unsigned long long)(0xFFFFFFFFu - (unsigned)(lane * 4 + j));

    float wsum = 0.f, my_g = 0.f, prevs = 0.f, minGap = 1e30f, s8 = 0.f;
    int my_i = 0;

    #pragma unroll
    for (int it = 0; it < 9; ++it) {
        unsigned long long bk = kw[0];
        if (kw[1] > bk) bk = kw[1];
        if (kw[2] > bk) bk = kw[2];
        if (kw[3] > bk) bk = kw[3];
        #pragma unroll
        for (int off = 1; off < 64; off <<= 1) {
            const unsigned long long ok = __shfl_xor(bk, off, 64);
            if (ok > bk) bk = ok;
        }
        const unsigned o = (unsigned)(bk >> 32);
        const float sv = finv(o);
        const int e = (int)(0xFFFFFFFFu - (unsigned)(bk & 0xFFFFFFFFu));
        const int ej = e & 3, el = e >> 2;
        const float gl = (ej == 0) ? g[0] : (ej == 1) ? g[1] : (ej == 2) ? g[2] : g[3];
        const float gv = __shfl(gl, el, 64);
        if (it < TOP_K) {
            wsum += gv;
            if (lane == it) { my_i = e; my_g = gv; }
            if (it == 7) s8 = sv;
        }
        if (it > 0) minGap = fminf(minGap, prevs - sv);
        prevs = sv;
        if (lane == el) {
            if (ej == 0) kw[0] = 0ull; else if (ej == 1) kw[1] = 0ull;
            else if (ej == 2) kw[2] = 0ull; else kw[3] = 0ull;
        }
    }

    if (minGap < MARGIN) {
        int pos = 0;
        if (lane == 0) pos = atomicAdd(nmarg, 1);
        pos = __shfl(pos, 0, 64);
        const float thresh = s8 - MARGIN;
        int base = 0;
        #pragma unroll
        for (int j = 0; j < 4; ++j) {
            const bool c = (s0[j] >= thresh);
            const unsigned long long mk = __ballot(c);
            const int mypos = base + __popcll(mk & ((1ull << lane) - 1ull));
            if (c && mypos < 64) cand[(size_t)pos * 64 + mypos] = lane * 4 + j;
            base += (int)__popcll(mk);
        }
        if (lane == 0) { list[pos] = t; ncand[pos] = min(base, 64); }
    } else {
        const float inv = 1.f / (wsum + 1e-10f);
        if (lane < TOP_K) {
            out_idx[(size_t)t * TOP_K + lane] = (float)my_i;
            out_w[(size_t)t * TOP_K + lane] = my_g * inv;
        }
    }
}

// ---------------------------------------------------------------------------
// Kernel R: candidate-set f64 recheck. R4-exact.
// ---------------------------------------------------------------------------
__global__ __launch_bounds__(256) void recheck2(
    const float* __restrict__ H, const double* __restrict__ M64,
    const float* __restrict__ bias, const int* __restrict__ list,
    const int* __restrict__ ncand, const int* __restrict__ cand,
    const int* __restrict__ nmarg, float* __restrict__ out_idx,
    float* __restrict__ out_w)
{
    __shared__ float hsf[D_MODEL];
    __shared__ double sg[64], ssc[64];

    const int n = *nmarg;
    const int lane = threadIdx.x & 63, wv = threadIdx.x >> 6;

    for (int i = (int)blockIdx.x; i < n; i += (int)gridDim.x) {
        const int t = list[i];
        const int nc = ncand[i];

        for (int qd = threadIdx.x; qd < D_MODEL / 4; qd += 256)
            *(float4*)&hsf[qd * 4] = *(const float4*)(H + (size_t)t * D_MODEL + qd * 4);
        __syncthreads();

        for (int c = wv; c < nc; c += 4) {
            const int e = cand[(size_t)i * 64 + c];
            const double* mrow = M64 + (size_t)e * D_MODEL;
            double acc = 0.0;
            #pragma unroll 8
            for (int j = 0; j < 32; ++j) {
                const int k = lane + 64 * j;
                acc = fma((double)hsf[k], mrow[k], acc);
            }
            #pragma unroll
            for (int off = 1; off < 64; off <<= 1) acc += __shfl_xor(acc, off, 64);
            if (lane == 0) {
                const double gg = 1.0 / (1.0 + exp(-acc));
                sg[c] = gg;
                ssc[c] = gg + (double)bias[e];
            }
        }
        __syncthreads();

        if (wv == 0) {
            double s = -1e300, g = 0.0;
            int id = 1 << 20;
            if (lane < nc) { s = ssc[lane]; g = sg[lane]; id = cand[(size_t)i * 64 + lane]; }

            double wsum = 0.0, my_g = 0.0;
            int my_i = 0;
            for (int it = 0; it < TOP_K; ++it) {
                double bs = s, bg = g; int bi = id;
                #pragma unroll
                for (int off = 1; off < 64; off <<= 1) {
                    const double os = __shfl_xor(bs, off, 64);
                    const double og = __shfl_xor(bg, off, 64);
                    const int    oi = __shfl_xor(bi, off, 64);
                    if (os > bs || (os == bs && oi < bi)) { bs = os; bg = og; bi = oi; }
                }
                wsum += bg;
                if (lane == it) { my_i = bi; my_g = bg; }
                if (id == bi) s = -1e300;
            }
            const double inv = 1.0 / (wsum + 1e-10);
            if (lane < TOP_K) {
                out_idx[(size_t)t * TOP_K + lane] = (float)my_i;
                out_w[(size_t)t * TOP_K + lane] = (float)(my_g * inv);
            }
        }
        __syncthreads();
    }
}

// ---------------------------------------------------------------------------
// Kernel H: histogram out_idx -> counts; reduce colsumPart -> sumP; the
// LAST block (ticket pattern) computes the balance loss. grid 64 x 256.
// colsumPart is [2][256][128]. R4-exact.
// ---------------------------------------------------------------------------
__global__ __launch_bounds__(256) void hist_reduce_loss(
    const float* __restrict__ out_idx, const float* __restrict__ colsumPart,
    int* __restrict__ counts, double* __restrict__ sumP,
    int* __restrict__ done, float* __restrict__ out_loss)
{
    __shared__ int h[NUM_EXPERTS];
    __shared__ int ticket;
    const int tid = threadIdx.x;
    const int lane = tid & 63, wv = tid >> 6;
    h[tid] = 0;
    __syncthreads();
    for (int i = (int)blockIdx.x * 256 + tid; i < T_TOKENS * TOP_K; i += 64 * 256)
        atomicAdd(&h[(int)out_idx[i]], 1);
    __syncthreads();
    if (h[tid] != 0) atomicAdd(&counts[tid], h[tid]);

    const int e = (int)blockIdx.x * 4 + wv;
    const int half = e >> 7, el = e & 127;
    float ps = 0.f;
    for (int p = lane; p < 256; p += 64)
        ps += colsumPart[((size_t)half * 256 + p) * 128 + el];
    #pragma unroll
    for (int off = 1; off < 64; off <<= 1) ps += __shfl_xor(ps, off, 64);
    if (lane == 0) sumP[e] = (double)ps;

    __threadfence();
    __syncthreads();
    if (tid == 0) ticket = atomicAdd(done, 1);
    __syncthreads();
    if (ticket == 63) {
        __shared__ double red[256];
        const int c = atomicAdd(&counts[tid], 0);
        const double sp = atomicAdd(&sumP[tid], 0.0);
        red[tid] = (double)c * sp;
        __syncthreads();
        #pragma unroll
        for (int sft = 128; sft > 0; sft >>= 1) {
            if (tid < sft) red[tid] += red[tid + sft];
            __syncthreads();
        }
        if (tid == 0) {
            const double denom = (double)T_TOKENS * (double)TOP_K * (double)T_TOKENS;
            out_loss[0] = (float)(0.001 * ((double)NUM_EXPERTS / (double)TOP_K) * red[0] / denom);
        }
    }
}

extern "C" void kernel_launch(void* const* d_in, const int* in_sizes, int n_in,
                              void* d_out, int out_size, void* d_ws, size_t ws_size,
                              hipStream_t stream) {
    (void)in_sizes; (void)n_in; (void)out_size; (void)ws_size;
    const float* hidden = (const float*)d_in[0];
    const float* W      = (const float*)d_in[1];
    const float* C      = (const float*)d_in[2];
    const float* bias   = (const float*)d_in[3];
    float* out = (float*)d_out;
    char* ws   = (char*)d_ws;

    double*         M64    = (double*)(ws + WS_M64_B);
    unsigned short* Mh     = (unsigned short*)(ws + WS_MH_B);
    unsigned short* Ml     = (unsigned short*)(ws + WS_ML_B);
    double*         sumP   = (double*)(ws + WS_SUMP_B);
    int*            counts = (int*)(ws + WS_CNT_B);
    int*            nmarg  = (int*)(ws + WS_NMARG_B);
    int*            done   = (int*)(ws + WS_NMARG_B) + 1;
    int*            list   = (int*)(ws + WS_LIST_B);
    int*            ncand  = (int*)(ws + WS_NCAND_B);
    int*            cand   = (int*)(ws + WS_CAND_B);
    float*          csp    = (float*)(ws + WS_CSP_B);
    double*         Mpart  = (double*)(ws + WS_MP_B);

    hipMemsetAsync(ws + WS_CNT_B, 0, NUM_EXPERTS * 4 + 16, stream);

    cw_gemm_part<<<dim3(D_MODEL / 64, NUM_EXPERTS / 32, 4), 256, 0, stream>>>(C, W, Mpart);
    cw_combine<<<dim3(NUM_EXPERTS * D_MODEL / 1024), 256, 0, stream>>>(Mpart, M64, Mh, Ml);

    affinity_mfma<<<dim3(T_TOKENS / 64, 2), 512, 0, stream>>>(hidden, Mh, Ml, out + OUT_AFF, csp);

    topk_margin<<<dim3(T_TOKENS / 4), 256, 0, stream>>>(
        out + OUT_AFF, bias, out + OUT_IDX, out + OUT_W, nmarg, list, ncand, cand);

    recheck2<<<dim3(2048), 256, 0, stream>>>(
        hidden, M64, bias, list, ncand, cand, nmarg, out + OUT_IDX, out + OUT_W);

    hist_reduce_loss<<<dim3(64), 256, 0, stream>>>(
        out + OUT_IDX, csp, counts, sumP, done, out + OUT_LOSS);
}